// Round 2
// baseline (659.661 us; speedup 1.0000x reference)
//
#include <hip/hip_runtime.h>
#include <math.h>

// Volume geometry (1,1,96,128,128)
#define DIMD 96
#define DIMH 128
#define DIMW 128
#define N_ELEM (DIMD*DIMH*DIMW)   // 1,572,864
#define N4 (N_ELEM/4)

#define RBLOCKS 512

__device__ __forceinline__ float sigmoidf_(float x) { return 1.0f / (1.0f + expf(-x)); }
__device__ __forceinline__ float4 mk4(float a, float b, float c, float d) {
    float4 r; r.x = a; r.y = b; r.z = c; r.w = d; return r;
}
__device__ __forceinline__ float4 ldf4(const float* p) { return *(const float4*)p; }

template<bool MX> __device__ __forceinline__ float op2(float a, float b) {
    return MX ? fmaxf(a, b) : fminf(a, b);
}
template<bool MX> __device__ __forceinline__ float op3(float a, float b, float c) {
    return op2<MX>(op2<MX>(a, b), c);   // compiler -> v_min3/v_max3
}
template<bool MX> __device__ __forceinline__ float4 vop(float4 a, float4 b) {
    return mk4(op2<MX>(a.x,b.x), op2<MX>(a.y,b.y), op2<MX>(a.z,b.z), op2<MX>(a.w,b.w));
}
// shifted 3-window min/max over 4 consecutive x-outputs from 2 aligned float4s:
// out[i] = op(v[i], v[i+1], v[i+2]) where v = concat(A,B)
template<bool MX> __device__ __forceinline__ float4 shift3(float4 A, float4 B) {
    return mk4(op3<MX>(A.x,A.y,A.z), op3<MX>(A.y,A.z,A.w),
               op3<MX>(A.z,A.w,B.x), op3<MX>(A.w,B.x,B.y));
}

// Generic 3x3x3 min/max stage over an LDS region, z-separable via register ring.
// dst[z][y][x] = op over src[z..z+2][y..y+2][x..x+2]  (local index chain, origin shifts +1)
// Out-of-volume outputs are masked to the NEXT stage's neutral (+inf before erode,
// -inf before dilate) so chained stages get exact skip-OOB (-inf pad) semantics.
// ox,oy,oz = global coords of dst local (0,0,0).
template<bool MX, bool NEXTMX, int SROW, int SPL, int DROW, int DPL, int NZ, int WQ, int NY>
__device__ __forceinline__ void stage(const float* src, float* dst, int tid,
                                      int ox, int oy, int oz) {
    if (tid >= WQ * NY) return;
    const int xq = tid % WQ, y = tid / WQ;
    const float NEUT = NEXTMX ? -INFINITY : INFINITY;
    const int gy  = oy + y;
    const int gx0 = ox + xq * 4;
    const bool oky = ((unsigned)gy < DIMH);
    float4 ring[3];
    #pragma unroll
    for (int z = 0; z < NZ + 2; ++z) {
        float4 xym;
        #pragma unroll
        for (int dy = 0; dy < 3; ++dy) {
            const float* row = src + z * SPL + (y + dy) * SROW + xq * 4;
            float4 m = shift3<MX>(ldf4(row), ldf4(row + 4));
            xym = dy ? vop<MX>(xym, m) : m;
        }
        ring[z % 3] = xym;
        if (z >= 2) {
            const int zd = z - 2;
            float4 r = vop<MX>(vop<MX>(ring[0], ring[1]), ring[2]);
            const int gz = oz + zd;
            const bool ok = oky && ((unsigned)gz < DIMD);
            r.x = (ok && (unsigned)(gx0 + 0) < DIMW) ? r.x : NEUT;
            r.y = (ok && (unsigned)(gx0 + 1) < DIMW) ? r.y : NEUT;
            r.z = (ok && (unsigned)(gx0 + 2) < DIMW) ? r.z : NEUT;
            r.w = (ok && (unsigned)(gx0 + 3) < DIMW) ? r.w : NEUT;
            *(float4*)(dst + zd * DPL + y * DROW + xq * 4) = r;
        }
    }
}

// Final dilate stage + epilogue. sb = dilate input, [8][18][36] (row 36, plane 648).
// aux = field at output position, [10][20][36] layout (plane 720), offset (+2,+2,+2).
// EPI 1: skel[gi] = relu(aux - D)                    (skeleton init; dimg unused)
// EPI 2: delta = relu(aux - D); skel += relu(delta - skel*delta); dimg[gi] = aux
template<int EPI>
__device__ __forceinline__ void final_stage(const float* sb, const float* aux,
                                            float* skel, float* dimg,
                                            int bx, int by, int bz, int vol, int tid) {
    if (tid >= 128) return;
    const int xq = tid & 7, y = tid >> 3;
    float4 ring[3];
    #pragma unroll
    for (int z = 0; z < 8; ++z) {
        float4 xym;
        #pragma unroll
        for (int dy = 0; dy < 3; ++dy) {
            const float* row = sb + z * 648 + (y + dy) * 36 + xq * 4;
            float4 m = shift3<true>(ldf4(row), ldf4(row + 4));
            xym = dy ? vop<true>(xym, m) : m;
        }
        ring[z % 3] = xym;
        if (z >= 2) {
            const int oz = z - 2;
            float4 D = vop<true>(vop<true>(ring[0], ring[1]), ring[2]);
            const float* ar = aux + (oz + 2) * 720 + (y + 2) * 36 + xq * 4;
            float4 P = ldf4(ar), Q = ldf4(ar + 4);
            float4 av = mk4(P.z, P.w, Q.x, Q.y);   // aux at x offset +2
            size_t gi = (size_t)vol * N_ELEM +
                        ((size_t)(bz + oz) * DIMH + (by + y)) * DIMW + bx + xq * 4;
            float4 dl = mk4(fmaxf(av.x - D.x, 0.f), fmaxf(av.y - D.y, 0.f),
                            fmaxf(av.z - D.z, 0.f), fmaxf(av.w - D.w, 0.f));
            if (EPI == 1) {
                *(float4*)(skel + gi) = dl;
            } else {
                float4 sk = ldf4(skel + gi);
                sk.x += fmaxf(dl.x - sk.x * dl.x, 0.f);
                sk.y += fmaxf(dl.y - sk.y * dl.y, 0.f);
                sk.z += fmaxf(dl.z - sk.z * dl.z, 0.f);
                sk.w += fmaxf(dl.w - sk.w * dl.w, 0.f);
                *(float4*)(skel + gi) = sk;
                *(float4*)(dimg + gi) = av;
            }
        }
    }
}

// -------- prologue: img[0..N) = sigmoid(sigmoid(y_pred)); img[N..2N) = y_true --------
__global__ __launch_bounds__(256) void prologue_kernel(const float* __restrict__ yp,
                                                       const float* __restrict__ yt,
                                                       float* __restrict__ img) {
    int i = blockIdx.x * 256 + threadIdx.x;
    if (i < N4) {
        float4 a = ldf4(yp + i * 4);
        float4 b = ldf4(yt + i * 4);
        float4 s = mk4(sigmoidf_(sigmoidf_(a.x)), sigmoidf_(sigmoidf_(a.y)),
                       sigmoidf_(sigmoidf_(a.z)), sigmoidf_(sigmoidf_(a.w)));
        *(float4*)(img + i * 4) = s;
        *(float4*)(img + N_ELEM + i * 4) = b;
    }
}

// -------- init: skel = relu(img - dilate(erode(img))) --------
// tile 32x16x6, halo 2. img region [10][20][36] (z: bz-2.., y: by-2.., x: bx-2..bx+33)
__global__ __launch_bounds__(256) void init_kernel(const float* __restrict__ img,
                                                   float* __restrict__ skel) {
    __shared__ alignas(16) float bufA[7208];   // img [10][20][36] + guard
    __shared__ alignas(16) float bufB[5192];   // e1  [8][18][36]  + guard
    const int tid = threadIdx.x;
    const int vol = blockIdx.z >> 4, zc = blockIdx.z & 15;
    const int bx = blockIdx.x * 32, by = blockIdx.y * 16, bz = zc * 6;
    const float* s = img + (size_t)vol * N_ELEM;
    for (int f = tid; f < 10 * 20 * 36; f += 256) {
        int lz = f / 720; int r = f - lz * 720; int ly = r / 36; int lx = r - ly * 36;
        int gz = min(max(bz - 2 + lz, 0), DIMD - 1);
        int gy = min(max(by - 2 + ly, 0), DIMH - 1);
        int gx = min(max(bx - 2 + lx, 0), DIMW - 1);
        bufA[f] = s[((size_t)gz * DIMH + gy) * DIMW + gx];
    }
    __syncthreads();
    // erode img -> e1 (next stage is dilate -> mask OOB to -inf)
    stage<false, true, 36, 720, 36, 648, 8, 9, 18>(bufA, bufB, tid, bx - 1, by - 1, bz - 1);
    __syncthreads();
    final_stage<1>(bufB, bufA, skel, nullptr, bx, by, bz, vol, tid);
}

// -------- fused iteration: img_next = erode(img); open = dilate(erode(img_next));
//          delta = relu(img_next - open); skel += relu(delta - skel*delta) --------
// tile 32x16x6, halo 3. img region [12][22][40-stride, 38 used]
__global__ __launch_bounds__(256) void iter_kernel(const float* __restrict__ src,
                                                   float* __restrict__ dimg,
                                                   float* __restrict__ skel) {
    __shared__ alignas(16) float bufA[10560];  // img [12][22][40]; later e2 overlay [8][18][36]
    __shared__ alignas(16) float bufB[7208];   // e1  [10][20][36] + guard
    const int tid = threadIdx.x;
    const int vol = blockIdx.z >> 4, zc = blockIdx.z & 15;
    const int bx = blockIdx.x * 32, by = blockIdx.y * 16, bz = zc * 6;
    const float* s = src + (size_t)vol * N_ELEM;
    for (int f = tid; f < 12 * 22 * 38; f += 256) {
        int lz = f / 836; int r = f - lz * 836; int ly = r / 38; int lx = r - ly * 38;
        int gz = min(max(bz - 3 + lz, 0), DIMD - 1);
        int gy = min(max(by - 3 + ly, 0), DIMH - 1);
        int gx = min(max(bx - 3 + lx, 0), DIMW - 1);
        bufA[(lz * 22 + ly) * 40 + lx] = s[((size_t)gz * DIMH + gy) * DIMW + gx];
    }
    __syncthreads();
    // E1 = erode(img) -> bufB  (next stage erode -> mask OOB to +inf)
    stage<false, false, 40, 880, 36, 720, 10, 9, 20>(bufA, bufB, tid, bx - 2, by - 2, bz - 2);
    __syncthreads();
    // E2 = erode(E1) -> bufA overlay (next stage dilate -> mask OOB to -inf)
    stage<false, true, 36, 720, 36, 648, 8, 9, 18>(bufB, bufA, tid, bx - 1, by - 1, bz - 1);
    __syncthreads();
    // D = dilate(E2); epilogue: img_next (=E1 interior) + skel update
    final_stage<2>(bufA, bufB, skel, dimg, bx, by, bz, vol, tid);
}

// -------- reductions --------
__device__ __forceinline__ double wave_block_reduce(double v, double* red4) {
    for (int off = 32; off > 0; off >>= 1) v += __shfl_down(v, off, 64);
    int wid = threadIdx.x >> 6, lane = threadIdx.x & 63;
    if (lane == 0) red4[wid] = v;
    __syncthreads();
    double r = red4[0] + red4[1] + red4[2] + red4[3];
    __syncthreads();
    return r;
}

// 0: skel_pred*y_true  1: skel_pred  2: skel_true*s2  3: skel_true
// 4: w*s1*y_true       5: w*s1       6: w*y_true      (w = exp(-skel_true^2/2))
// 7: s1*y_true         8: s1         9: y_true
__global__ __launch_bounds__(256) void reduce_partial(const float* __restrict__ yp,
                                                      const float* __restrict__ yt,
                                                      const float* __restrict__ sp,
                                                      const float* __restrict__ st,
                                                      double* __restrict__ partials) {
    double acc[10];
    #pragma unroll
    for (int k = 0; k < 10; ++k) acc[k] = 0.0;

    for (int i = blockIdx.x * 256 + threadIdx.x; i < N4; i += RBLOCKS * 256) {
        float4 x = ldf4(yp + i * 4);
        float4 t = ldf4(yt + i * 4);
        float4 a = ldf4(sp + i * 4);
        float4 b = ldf4(st + i * 4);
        #pragma unroll
        for (int c = 0; c < 4; ++c) {
            float xc = (&x.x)[c], tc = (&t.x)[c], ac = (&a.x)[c], bc = (&b.x)[c];
            float s1 = sigmoidf_(xc);
            float s2 = sigmoidf_(s1);
            float w  = expf(-0.5f * bc * bc);
            acc[0] += (double)(ac * tc);
            acc[1] += (double)ac;
            acc[2] += (double)(bc * s2);
            acc[3] += (double)bc;
            acc[4] += (double)(w * s1 * tc);
            acc[5] += (double)(w * s1);
            acc[6] += (double)(w * tc);
            acc[7] += (double)(s1 * tc);
            acc[8] += (double)s1;
            acc[9] += (double)tc;
        }
    }

    __shared__ double red4[4];
    #pragma unroll
    for (int k = 0; k < 10; ++k) {
        double r = wave_block_reduce(acc[k], red4);
        if (threadIdx.x == 0) partials[blockIdx.x * 10 + k] = r;
        __syncthreads();
    }
}

__global__ __launch_bounds__(256) void finalize_kernel(const double* __restrict__ partials,
                                                       float* __restrict__ out) {
    __shared__ double sums[10];
    __shared__ double red4[4];
    for (int k = 0; k < 10; ++k) {
        double v = 0.0;
        for (int j = threadIdx.x; j < RBLOCKS; j += 256) v += partials[j * 10 + k];
        double r = wave_block_reduce(v, red4);
        if (threadIdx.x == 0) sums[k] = r;
        __syncthreads();
    }
    if (threadIdx.x == 0) {
        double tprec = (sums[0] + 1.0) / (sums[1] + 1.0);
        double tsens = (sums[2] + 1.0) / (sums[3] + 1.0);
        double cldice = 1.0 - 2.0 * (tprec * tsens) / (tprec + tsens + 1.0);
        double boundary = 1.0 - (2.0 * sums[4] + 1.0) / (sums[5] + sums[6] + 1.0);
        double dice = 1.0 - (2.0 * sums[7] + 1.0) / (sums[8] + sums[9] + 1.0);
        out[0] = (float)(0.5 * cldice + 0.3 * boundary + 0.2 * dice);
    }
}

extern "C" void kernel_launch(void* const* d_in, const int* in_sizes, int n_in,
                              void* d_out, int out_size, void* d_ws, size_t ws_size,
                              hipStream_t stream) {
    const float* y_pred = (const float*)d_in[0];
    const float* y_true = (const float*)d_in[1];
    float* out = (float*)d_out;

    const size_t NB = (size_t)2 * N_ELEM;
    float* imgA = (float*)d_ws;
    float* imgB = imgA + NB;
    float* skel = imgB + NB;
    double* partials = (double*)(skel + NB);

    dim3 g(DIMW / 32, DIMH / 16, (DIMD / 6) * 2);   // (4, 8, 32); z = vol*16 + zchunk
    dim3 b(256);

    prologue_kernel<<<(N4 + 255) / 256, 256, 0, stream>>>(y_pred, y_true, imgA);
    init_kernel<<<g, b, 0, stream>>>(imgA, skel);

    float* cur = imgA;
    float* nxt = imgB;
    for (int it = 0; it < 16; ++it) {
        iter_kernel<<<g, b, 0, stream>>>(cur, nxt, skel);
        float* tmp = cur; cur = nxt; nxt = tmp;
    }

    reduce_partial<<<RBLOCKS, 256, 0, stream>>>(y_pred, y_true, skel, skel + N_ELEM, partials);
    finalize_kernel<<<1, 256, 0, stream>>>(partials, out);
}

// Round 5
// 562.297 us; speedup vs baseline: 1.1732x; 1.1732x over previous
//
#include <hip/hip_runtime.h>
#include <math.h>

// Volume geometry (1,1,96,128,128)
#define DIMD 96
#define DIMH 128
#define DIMW 128
#define N_ELEM (DIMD*DIMH*DIMW)   // 1,572,864
#define N4 (N_ELEM/4)

#define RBLOCKS 512

__device__ __forceinline__ float sigmoidf_(float x) { return 1.0f / (1.0f + expf(-x)); }
__device__ __forceinline__ float4 mk4(float a, float b, float c, float d) {
    float4 r; r.x = a; r.y = b; r.z = c; r.w = d; return r;
}
__device__ __forceinline__ float4 ldf4(const float* p) { return *(const float4*)p; }

template<bool MX> __device__ __forceinline__ float op2(float a, float b) {
    return MX ? fmaxf(a, b) : fminf(a, b);
}
template<bool MX> __device__ __forceinline__ float op3(float a, float b, float c) {
    return op2<MX>(op2<MX>(a, b), c);   // -> v_min3/v_max3
}
template<bool MX> __device__ __forceinline__ float4 vop(float4 a, float4 b) {
    return mk4(op2<MX>(a.x,b.x), op2<MX>(a.y,b.y), op2<MX>(a.z,b.z), op2<MX>(a.w,b.w));
}
// out[i] = op(v[4q+i..4q+i+2]), v = concat(A,B): window start aligned with quad
template<bool MX> __device__ __forceinline__ float4 shift3(float4 A, float4 B) {
    return mk4(op3<MX>(A.x,A.y,A.z), op3<MX>(A.y,A.z,A.w),
               op3<MX>(A.z,A.w,B.x), op3<MX>(A.w,B.x,B.y));
}
// window start offset +1 within the quad pair
template<bool MX> __device__ __forceinline__ float4 shift3b(float4 A, float4 B) {
    return mk4(op3<MX>(A.y,A.z,A.w), op3<MX>(A.z,A.w,B.x),
               op3<MX>(A.w,B.x,B.y), op3<MX>(B.x,B.y,B.z));
}

// 3x3 xy min/max of an LDS plane at (row y.., quad xq), window start aligned
template<bool MX> __device__ __forceinline__ float4 xy3(const float* base, int stride, int y, int xq) {
    float4 acc;
    #pragma unroll
    for (int dy = 0; dy < 3; ++dy) {
        const float* row = base + (y + dy) * stride + xq * 4;
        float4 m = shift3<MX>(ldf4(row), ldf4(row + 4));
        acc = dy ? vop<MX>(acc, m) : m;
    }
    return acc;
}
template<bool MX> __device__ __forceinline__ float4 xy3b(const float* base, int stride, int y, int xq) {
    float4 acc;
    #pragma unroll
    for (int dy = 0; dy < 3; ++dy) {
        const float* row = base + (y + dy) * stride + xq * 4;
        float4 m = shift3b<MX>(ldf4(row), ldf4(row + 4));
        acc = dy ? vop<MX>(acc, m) : m;
    }
    return acc;
}

// mask stage outputs at out-of-volume positions to next stage's neutral
__device__ __forceinline__ float4 maskq(float4 v, int gx0, int gy, int gz, float NEUT) {
    const bool okzy = ((unsigned)gz < DIMD) & ((unsigned)gy < DIMH);
    float4 r;
    r.x = (okzy & ((unsigned)(gx0 + 0) < DIMW)) ? v.x : NEUT;
    r.y = (okzy & ((unsigned)(gx0 + 1) < DIMW)) ? v.y : NEUT;
    r.z = (okzy & ((unsigned)(gx0 + 2) < DIMW)) ? v.z : NEUT;
    r.w = (okzy & ((unsigned)(gx0 + 3) < DIMW)) ? v.w : NEUT;
    return r;
}

// -------- prologue --------
__global__ __launch_bounds__(256) void prologue_kernel(const float* __restrict__ yp,
                                                       const float* __restrict__ yt,
                                                       float* __restrict__ img) {
    int i = blockIdx.x * 256 + threadIdx.x;
    if (i < N4) {
        float4 a = ldf4(yp + i * 4);
        float4 b = ldf4(yt + i * 4);
        float4 s = mk4(sigmoidf_(sigmoidf_(a.x)), sigmoidf_(sigmoidf_(a.y)),
                       sigmoidf_(sigmoidf_(a.z)), sigmoidf_(sigmoidf_(a.w)));
        *(float4*)(img + i * 4) = s;
        *(float4*)(img + N_ELEM + i * 4) = b;
    }
}

// -------- init: skel = relu(img - dilate(erode(img))), z-streaming --------
// tile 32x16, z-chunk 6. Pipeline: A1=xy-min -> E1 (ring z-min, LDS) -> A2=xy-max -> D (ring) -> epilogue
__global__ __launch_bounds__(256) void init_kernel(const float* __restrict__ img,
                                                   float* __restrict__ skel) {
    __shared__ alignas(16) float IP[4][20 * 44];  // img planes, origin (bx-2, by-2), used 40 wide
    __shared__ alignas(16) float E1[18 * 36];     // erode plane, origin (bx-1, by-1), used 36 wide
    const int tid = threadIdx.x;
    const int vol = blockIdx.z >> 4, zc = blockIdx.z & 15;
    const int bx = blockIdx.x * 32, by = blockIdx.y * 16, bz = zc * 6;
    const float* s = img + (size_t)vol * N_ELEM;

    const int e1q = tid % 9, e1y = tid / 9;   // tid<162
    const int dq = tid & 7, dyy = tid >> 3;   // tid<128

    float4 r1a{}, r1b{}, r1c{}, r2a{}, r2b{}, r2c{};

    for (int st = 0; st < 10; ++st) {
        const int zp = bz - 2 + st;
        {
            const int zcl = min(max(zp, 0), DIMD - 1);
            const float* sp = s + (size_t)zcl * DIMH * DIMW;
            for (int f = tid; f < 20 * 40; f += 256) {
                int ly = f / 40, lx = f - ly * 40;
                int gy = min(max(by - 2 + ly, 0), DIMH - 1);
                int gx = min(max(bx - 2 + lx, 0), DIMW - 1);
                IP[st & 3][ly * 44 + lx] = sp[gy * DIMW + gx];
            }
        }
        __syncthreads();
        if (tid < 162) {
            float4 a1 = xy3<false>(IP[st & 3], 44, e1y, e1q);
            r1a = r1b; r1b = r1c; r1c = a1;
            if (st >= 2) {
                float4 e1 = vop<false>(vop<false>(r1a, r1b), r1c);
                e1 = maskq(e1, bx - 1 + e1q * 4, by - 1 + e1y, zp - 1, -INFINITY);
                *(float4*)&E1[e1y * 36 + e1q * 4] = e1;
            }
        }
        __syncthreads();
        if (tid < 128 && st >= 2) {
            float4 a2 = xy3<true>(E1, 36, dyy, dq);
            r2a = r2b; r2b = r2c; r2c = a2;
            if (st >= 4) {
                float4 D = vop<true>(vop<true>(r2a, r2b), r2c);
                const float* ar = &IP[(st - 2) & 3][(dyy + 2) * 44 + dq * 4];
                float4 P = ldf4(ar), Q = ldf4(ar + 4);
                float4 av = mk4(P.z, P.w, Q.x, Q.y);   // img at x offset +2 in plane coords
                const int zd = bz + st - 4;
                size_t gi = (size_t)vol * N_ELEM + ((size_t)zd * DIMH + (by + dyy)) * DIMW + bx + dq * 4;
                float4 dl = mk4(fmaxf(av.x - D.x, 0.f), fmaxf(av.y - D.y, 0.f),
                                fmaxf(av.z - D.z, 0.f), fmaxf(av.w - D.w, 0.f));
                *(float4*)(skel + gi) = dl;
            }
        }
        __syncthreads();
    }
}

// -------- fused iteration, z-streaming --------
// img_next = erode(img); open = dilate(erode(img_next)); delta = relu(img_next - open);
// skel += relu(delta - skel*delta); dimg = img_next
__global__ __launch_bounds__(256) void iter_kernel(const float* __restrict__ src,
                                                   float* __restrict__ dimg,
                                                   float* __restrict__ skel) {
    __shared__ alignas(16) float IP[2][22 * 52];  // img planes, origin (bx-4, by-3), used 44 wide
    __shared__ alignas(16) float E1[4][20 * 44];  // erode1 ring, origin (bx-3, by-2), used 40 wide
    __shared__ alignas(16) float E2[18 * 36];     // erode2 plane, origin (bx-2, by-1), used 36 wide
    const int tid = threadIdx.x;
    const int vol = blockIdx.z >> 4, zc = blockIdx.z & 15;
    const int bx = blockIdx.x * 32, by = blockIdx.y * 16, bz = zc * 6;
    const float* s = src + (size_t)vol * N_ELEM;

    const int e1q = tid % 10, e1y = tid / 10;  // tid<200
    const int e2q = tid % 9,  e2y = tid / 9;   // tid<162
    const int dq = tid & 7,   dyy = tid >> 3;  // tid<128

    float4 r1a{}, r1b{}, r1c{}, r2a{}, r2b{}, r2c{}, r3a{}, r3b{}, r3c{};

    for (int st = 0; st < 12; ++st) {
        const int zp = bz - 3 + st;
        {
            const int zcl = min(max(zp, 0), DIMD - 1);
            const float* sp = s + (size_t)zcl * DIMH * DIMW;
            for (int f = tid; f < 22 * 44; f += 256) {
                int ly = f / 44, lx = f - ly * 44;
                int gy = min(max(by - 3 + ly, 0), DIMH - 1);
                int gx = min(max(bx - 4 + lx, 0), DIMW - 1);
                IP[st & 1][ly * 52 + lx] = sp[gy * DIMW + gx];
            }
        }
        __syncthreads();
        // E1[zp-1] = erode(img), masked +inf outside volume (next stage erode)
        if (tid < 200) {
            float4 a1 = xy3<false>(IP[st & 1], 52, e1y, e1q);
            r1a = r1b; r1b = r1c; r1c = a1;
            if (st >= 2) {
                float4 e1 = vop<false>(vop<false>(r1a, r1b), r1c);
                e1 = maskq(e1, bx - 3 + e1q * 4, by - 2 + e1y, zp - 1, INFINITY);
                *(float4*)&E1[st & 3][e1y * 44 + e1q * 4] = e1;
            }
        }
        __syncthreads();
        // E2[zp-2] = erode(E1), masked -inf outside (next stage dilate)
        if (tid < 162 && st >= 2) {
            float4 a2 = xy3<false>(E1[st & 3], 44, e2y, e2q);
            r2a = r2b; r2b = r2c; r2c = a2;
            if (st >= 4) {
                float4 e2 = vop<false>(vop<false>(r2a, r2b), r2c);
                e2 = maskq(e2, bx - 2 + e2q * 4, by - 1 + e2y, zp - 2, -INFINITY);
                *(float4*)&E2[e2y * 36 + e2q * 4] = e2;
            }
        }
        __syncthreads();
        // D[zp-3] = dilate(E2); epilogue with E1[zd] (= img_next) from ring slot (st-2)&3
        if (tid < 128 && st >= 4) {
            float4 a3 = xy3b<true>(E2, 36, dyy, dq);
            r3a = r3b; r3b = r3c; r3c = a3;
            if (st >= 6) {
                float4 D = vop<true>(vop<true>(r3a, r3b), r3c);
                const float* ar = &E1[(st - 2) & 3][(dyy + 2) * 44 + dq * 4];
                float4 P = ldf4(ar), Q = ldf4(ar + 4);
                float4 av = mk4(P.w, Q.x, Q.y, Q.z);   // E1 at x offset +3 in plane coords
                const int zd = bz + st - 6;
                size_t gi = (size_t)vol * N_ELEM + ((size_t)zd * DIMH + (by + dyy)) * DIMW + bx + dq * 4;
                float4 dl = mk4(fmaxf(av.x - D.x, 0.f), fmaxf(av.y - D.y, 0.f),
                                fmaxf(av.z - D.z, 0.f), fmaxf(av.w - D.w, 0.f));
                float4 sk = ldf4(skel + gi);
                sk.x += fmaxf(dl.x - sk.x * dl.x, 0.f);
                sk.y += fmaxf(dl.y - sk.y * dl.y, 0.f);
                sk.z += fmaxf(dl.z - sk.z * dl.z, 0.f);
                sk.w += fmaxf(dl.w - sk.w * dl.w, 0.f);
                *(float4*)(skel + gi) = sk;
                *(float4*)(dimg + gi) = av;
            }
        }
    }
}

// -------- reductions --------
__device__ __forceinline__ double wave_block_reduce(double v, double* red4) {
    for (int off = 32; off > 0; off >>= 1) v += __shfl_down(v, off, 64);
    int wid = threadIdx.x >> 6, lane = threadIdx.x & 63;
    if (lane == 0) red4[wid] = v;
    __syncthreads();
    double r = red4[0] + red4[1] + red4[2] + red4[3];
    __syncthreads();
    return r;
}

// 0: skel_pred*y_true  1: skel_pred  2: skel_true*s2  3: skel_true
// 4: w*s1*y_true       5: w*s1       6: w*y_true      (w = exp(-skel_true^2/2))
// 7: s1*y_true         8: s1         9: y_true
__global__ __launch_bounds__(256) void reduce_partial(const float* __restrict__ yp,
                                                      const float* __restrict__ yt,
                                                      const float* __restrict__ sp,
                                                      const float* __restrict__ st,
                                                      double* __restrict__ partials) {
    double acc[10];
    #pragma unroll
    for (int k = 0; k < 10; ++k) acc[k] = 0.0;

    for (int i = blockIdx.x * 256 + threadIdx.x; i < N4; i += RBLOCKS * 256) {
        float4 x = ldf4(yp + i * 4);
        float4 t = ldf4(yt + i * 4);
        float4 a = ldf4(sp + i * 4);
        float4 b = ldf4(st + i * 4);
        #pragma unroll
        for (int c = 0; c < 4; ++c) {
            float xc = (&x.x)[c], tc = (&t.x)[c], ac = (&a.x)[c], bc = (&b.x)[c];
            float s1 = sigmoidf_(xc);
            float s2 = sigmoidf_(s1);
            float w  = expf(-0.5f * bc * bc);
            acc[0] += (double)(ac * tc);
            acc[1] += (double)ac;
            acc[2] += (double)(bc * s2);
            acc[3] += (double)bc;
            acc[4] += (double)(w * s1 * tc);
            acc[5] += (double)(w * s1);
            acc[6] += (double)(w * tc);
            acc[7] += (double)(s1 * tc);
            acc[8] += (double)s1;
            acc[9] += (double)tc;
        }
    }

    __shared__ double red4[4];
    #pragma unroll
    for (int k = 0; k < 10; ++k) {
        double r = wave_block_reduce(acc[k], red4);
        if (threadIdx.x == 0) partials[blockIdx.x * 10 + k] = r;
        __syncthreads();
    }
}

__global__ __launch_bounds__(256) void finalize_kernel(const double* __restrict__ partials,
                                                       float* __restrict__ out) {
    __shared__ double sums[10];
    __shared__ double red4[4];
    for (int k = 0; k < 10; ++k) {
        double v = 0.0;
        for (int j = threadIdx.x; j < RBLOCKS; j += 256) v += partials[j * 10 + k];
        double r = wave_block_reduce(v, red4);
        if (threadIdx.x == 0) sums[k] = r;
        __syncthreads();
    }
    if (threadIdx.x == 0) {
        double tprec = (sums[0] + 1.0) / (sums[1] + 1.0);
        double tsens = (sums[2] + 1.0) / (sums[3] + 1.0);
        double cldice = 1.0 - 2.0 * (tprec * tsens) / (tprec + tsens + 1.0);
        double boundary = 1.0 - (2.0 * sums[4] + 1.0) / (sums[5] + sums[6] + 1.0);
        double dice = 1.0 - (2.0 * sums[7] + 1.0) / (sums[8] + sums[9] + 1.0);
        out[0] = (float)(0.5 * cldice + 0.3 * boundary + 0.2 * dice);
    }
}

extern "C" void kernel_launch(void* const* d_in, const int* in_sizes, int n_in,
                              void* d_out, int out_size, void* d_ws, size_t ws_size,
                              hipStream_t stream) {
    const float* y_pred = (const float*)d_in[0];
    const float* y_true = (const float*)d_in[1];
    float* out = (float*)d_out;

    const size_t NB = (size_t)2 * N_ELEM;
    float* imgA = (float*)d_ws;
    float* imgB = imgA + NB;
    float* skel = imgB + NB;
    double* partials = (double*)(skel + NB);

    dim3 g(DIMW / 32, DIMH / 16, 16 * 2);   // (4, 8, 32); z = vol*16 + zchunk(6 deep)
    dim3 b(256);

    prologue_kernel<<<(N4 + 255) / 256, 256, 0, stream>>>(y_pred, y_true, imgA);
    init_kernel<<<g, b, 0, stream>>>(imgA, skel);

    float* cur = imgA;
    float* nxt = imgB;
    for (int it = 0; it < 16; ++it) {
        iter_kernel<<<g, b, 0, stream>>>(cur, nxt, skel);
        float* tmp = cur; cur = nxt; nxt = tmp;
    }

    reduce_partial<<<RBLOCKS, 256, 0, stream>>>(y_pred, y_true, skel, skel + N_ELEM, partials);
    finalize_kernel<<<1, 256, 0, stream>>>(partials, out);
}

// Round 6
// 429.596 us; speedup vs baseline: 1.5355x; 1.3089x over previous
//
#include <hip/hip_runtime.h>
#include <math.h>

// Volume geometry (1,1,96,128,128)
#define DIMD 96
#define DIMH 128
#define DIMW 128
#define N_ELEM (DIMD*DIMH*DIMW)   // 1,572,864
#define N4 (N_ELEM/4)

#define RBLOCKS 512

__device__ __forceinline__ float sigmoidf_(float x) { return 1.0f / (1.0f + expf(-x)); }
__device__ __forceinline__ float4 mk4(float a, float b, float c, float d) {
    float4 r; r.x = a; r.y = b; r.z = c; r.w = d; return r;
}
__device__ __forceinline__ float4 ldf4(const float* p) { return *(const float4*)p; }

template<bool MX> __device__ __forceinline__ float op2(float a, float b) {
    return MX ? fmaxf(a, b) : fminf(a, b);
}
template<bool MX> __device__ __forceinline__ float op3(float a, float b, float c) {
    return op2<MX>(op2<MX>(a, b), c);   // -> v_min3/v_max3
}
template<bool MX> __device__ __forceinline__ float4 vop(float4 a, float4 b) {
    return mk4(op2<MX>(a.x,b.x), op2<MX>(a.y,b.y), op2<MX>(a.z,b.z), op2<MX>(a.w,b.w));
}
// out[i] = op(v[i..i+2]), v = concat(A,B), window start aligned with quad
template<bool MX> __device__ __forceinline__ float4 shift3(float4 A, float4 B) {
    return mk4(op3<MX>(A.x,A.y,A.z), op3<MX>(A.y,A.z,A.w),
               op3<MX>(A.z,A.w,B.x), op3<MX>(A.w,B.x,B.y));
}
// window start offset +1 within the quad pair
template<bool MX> __device__ __forceinline__ float4 shift3b(float4 A, float4 B) {
    return mk4(op3<MX>(A.y,A.z,A.w), op3<MX>(A.z,A.w,B.x),
               op3<MX>(A.w,B.x,B.y), op3<MX>(B.x,B.y,B.z));
}
template<bool MX> __device__ __forceinline__ float4 xy3(const float* base, int stride, int y, int xq) {
    float4 acc;
    #pragma unroll
    for (int dy = 0; dy < 3; ++dy) {
        const float* row = base + (y + dy) * stride + xq * 4;
        float4 m = shift3<MX>(ldf4(row), ldf4(row + 4));
        acc = dy ? vop<MX>(acc, m) : m;
    }
    return acc;
}
template<bool MX> __device__ __forceinline__ float4 xy3b(const float* base, int stride, int y, int xq) {
    float4 acc;
    #pragma unroll
    for (int dy = 0; dy < 3; ++dy) {
        const float* row = base + (y + dy) * stride + xq * 4;
        float4 m = shift3b<MX>(ldf4(row), ldf4(row + 4));
        acc = dy ? vop<MX>(acc, m) : m;
    }
    return acc;
}
__device__ __forceinline__ float4 maskq(float4 v, int gx0, int gy, int gz, float NEUT) {
    const bool okzy = ((unsigned)gz < DIMD) & ((unsigned)gy < DIMH);
    float4 r;
    r.x = (okzy & ((unsigned)(gx0 + 0) < DIMW)) ? v.x : NEUT;
    r.y = (okzy & ((unsigned)(gx0 + 1) < DIMW)) ? v.y : NEUT;
    r.z = (okzy & ((unsigned)(gx0 + 2) < DIMW)) ? v.z : NEUT;
    r.w = (okzy & ((unsigned)(gx0 + 3) < DIMW)) ? v.w : NEUT;
    return r;
}

// -------- prologue --------
__global__ __launch_bounds__(256) void prologue_kernel(const float* __restrict__ yp,
                                                       const float* __restrict__ yt,
                                                       float* __restrict__ img) {
    int i = blockIdx.x * 256 + threadIdx.x;
    if (i < N4) {
        float4 a = ldf4(yp + i * 4);
        float4 b = ldf4(yt + i * 4);
        float4 s = mk4(sigmoidf_(sigmoidf_(a.x)), sigmoidf_(sigmoidf_(a.y)),
                       sigmoidf_(sigmoidf_(a.z)), sigmoidf_(sigmoidf_(a.w)));
        *(float4*)(img + i * 4) = s;
        *(float4*)(img + N_ELEM + i * 4) = b;
    }
}

// -------- init: skel = relu(img - dilate(erode(img))) --------
// Skewed single-barrier pipeline, tile 32x16, z-chunk 12.
// Per step st: load G(st)=bz-2+st (st<16); A1min on IP slot (st-1)%5 -> E1 write (st in [3,16]);
// A2max on E1 slot (st-1)&3 -> D + epilogue (st in [6,17], zd = bz-6+st, img from IP slot (st-4)%5).
__global__ __launch_bounds__(256) void init_kernel(const float* __restrict__ img,
                                                   float* __restrict__ skel) {
    __shared__ alignas(16) float IP[5][20 * 44];  // origin (bx-2, by-2), used 40 wide
    __shared__ alignas(16) float E1[4][18 * 36];  // origin (bx-1, by-1)
    const int tid = threadIdx.x;
    const int vol = blockIdx.z >> 3, zc = blockIdx.z & 7;
    const int bx = blockIdx.x * 32, by = blockIdx.y * 16, bz = zc * 12;
    const float* s = img + (size_t)vol * N_ELEM;

    const int e1id = (tid < 162) ? tid : -1;                         // 9q x 18r
    const int did  = (tid >= 162) ? tid - 162 : (tid < 34 ? tid + 94 : -1);  // 8q x 16r
    const int e1q = (e1id >= 0) ? e1id % 9 : 0, e1y = (e1id >= 0) ? e1id / 9 : 0;
    const int dq  = (did  >= 0) ? (did & 7) : 0, dyy = (did >= 0) ? (did >> 3) : 0;

    // precompute load offsets (20x40 = 800 elems)
    int goff[4], loff[4]; bool fok[4];
    #pragma unroll
    for (int k = 0; k < 4; ++k) {
        int f = tid + k * 256;
        fok[k] = f < 800;
        int ly = f / 40, lx = f - ly * 40;
        int gy = min(max(by - 2 + ly, 0), DIMH - 1);
        int gx = min(max(bx - 2 + lx, 0), DIMW - 1);
        goff[k] = fok[k] ? gy * DIMW + gx : 0;
        loff[k] = ly * 44 + lx;
    }

    float4 r1a{}, r1b{}, r1c{}, r2a{}, r2b{}, r2c{};

    for (int st = 0; st < 18; ++st) {
        // 1. issue global loads for plane G(st) = bz-2+st
        float lv[4];
        if (st < 16) {
            const int zcl = min(max(bz - 2 + st, 0), DIMD - 1);
            const float* sp = s + (size_t)zcl * DIMH * DIMW;
            #pragma unroll
            for (int k = 0; k < 4; ++k) lv[k] = sp[goff[k]];
        }
        // 2a. E1 stage: A1 = xy-min of IP plane G(st-1); E1 center G(st-2) = bz-4+st
        if (e1id >= 0 && st >= 1 && st <= 16) {
            float4 a1 = xy3<false>(IP[(st - 1) % 5], 44, e1y, e1q);
            r1a = r1b; r1b = r1c; r1c = a1;
            if (st >= 3) {
                float4 e1 = vop<false>(vop<false>(r1a, r1b), r1c);
                e1 = maskq(e1, bx - 1 + e1q * 4, by - 1 + e1y, bz - 4 + st, -INFINITY);
                *(float4*)&E1[st & 3][e1y * 36 + e1q * 4] = e1;
            }
        }
        // 2b. D stage: A2 = xy-max of E1 plane (st-1); D center zd = bz-6+st
        if (did >= 0 && st >= 4 && st <= 17) {
            float4 a2 = xy3<true>(E1[(st - 1) & 3], 36, dyy, dq);
            r2a = r2b; r2b = r2c; r2c = a2;
            if (st >= 6) {
                float4 D = vop<true>(vop<true>(r2a, r2b), r2c);
                const float* ar = &IP[(st - 4) % 5][(dyy + 2) * 44 + dq * 4];
                float4 P = ldf4(ar), Q = ldf4(ar + 4);
                float4 av = mk4(P.z, P.w, Q.x, Q.y);   // img at x offset +2
                const int zd = bz - 6 + st;
                size_t gi = (size_t)vol * N_ELEM + ((size_t)zd * DIMH + (by + dyy)) * DIMW + bx + dq * 4;
                float4 dl = mk4(fmaxf(av.x - D.x, 0.f), fmaxf(av.y - D.y, 0.f),
                                fmaxf(av.z - D.z, 0.f), fmaxf(av.w - D.w, 0.f));
                *(float4*)(skel + gi) = dl;
            }
        }
        // 3. commit loaded plane to IP ring
        if (st < 16) {
            float* dp = IP[st % 5];
            #pragma unroll
            for (int k = 0; k < 4; ++k) if (fok[k]) dp[loff[k]] = lv[k];
        }
        __syncthreads();
    }
}

// -------- fused iteration, skewed single-barrier pipeline --------
// img_next = erode(img); open = dilate(erode(img_next)); delta = relu(img_next - open);
// skel += relu(delta - skel*delta); dimg = img_next
// tile 32x16, z-chunk 12, 21 steps. G(st)=bz-3+st (st<18).
// E1 (erode img)  : A1 on IP slot (st-1)&3, write st in [3,18], plane bz-5+st, mask +inf
// E2 (erode E1)   : A2 on E1 slot (st-1)%5, write st in [6,19], plane bz-7+st, mask -inf
// D  (dilate E2)  : A3 on E2 slot (st-1)&3, out  st in [9,20], zd = bz-9+st; E1(zd) from slot (st-4)%5
__global__ __launch_bounds__(256) void iter_kernel(const float* __restrict__ src,
                                                   float* __restrict__ dimg,
                                                   float* __restrict__ skel) {
    __shared__ alignas(16) float IP[4][22 * 52];  // origin (bx-4, by-3), used 44 wide
    __shared__ alignas(16) float E1[5][20 * 44];  // origin (bx-3, by-2), used 40 wide
    __shared__ alignas(16) float E2[4][18 * 36];  // origin (bx-2, by-1)
    const int tid = threadIdx.x;
    const int vol = blockIdx.z >> 3, zc = blockIdx.z & 7;
    const int bx = blockIdx.x * 32, by = blockIdx.y * 16, bz = zc * 12;
    const float* s = src + (size_t)vol * N_ELEM;

    // task decode: E1 200 tasks (10q x 20r), E2 162 (9q x 18r), D 128 (8q x 16r); <=2 per thread
    const int e1id = (tid < 200) ? tid : -1;
    const int e2id = (tid >= 200) ? (tid - 200) : (tid < 106 ? tid + 56 : -1);
    const int did  = (tid >= 106 && tid < 234) ? (tid - 106) : -1;
    const int e1q = (e1id >= 0) ? e1id % 10 : 0, e1y = (e1id >= 0) ? e1id / 10 : 0;
    const int e2q = (e2id >= 0) ? e2id % 9  : 0, e2y = (e2id >= 0) ? e2id / 9  : 0;
    const int dq  = (did  >= 0) ? (did & 7) : 0, dyy = (did >= 0) ? (did >> 3) : 0;

    // precompute load offsets (22x44 = 968 elems)
    int goff[4], loff[4]; bool fok[4];
    #pragma unroll
    for (int k = 0; k < 4; ++k) {
        int f = tid + k * 256;
        fok[k] = f < 968;
        int ly = f / 44, lx = f - ly * 44;
        int gy = min(max(by - 3 + ly, 0), DIMH - 1);
        int gx = min(max(bx - 4 + lx, 0), DIMW - 1);
        goff[k] = fok[k] ? gy * DIMW + gx : 0;
        loff[k] = ly * 52 + lx;
    }

    float4 r1a{}, r1b{}, r1c{}, r2a{}, r2b{}, r2c{}, r3a{}, r3b{}, r3c{};

    for (int st = 0; st < 21; ++st) {
        // 1. issue global loads for plane G(st) = bz-3+st
        float lv[4];
        if (st < 18) {
            const int zcl = min(max(bz - 3 + st, 0), DIMD - 1);
            const float* sp = s + (size_t)zcl * DIMH * DIMW;
            #pragma unroll
            for (int k = 0; k < 4; ++k) lv[k] = sp[goff[k]];
        }
        // 2a. E1: A1 = xy-min of IP plane G(st-1); write plane bz-5+st (mask +inf; next is erode)
        if (e1id >= 0 && st >= 1 && st <= 18) {
            float4 a1 = xy3<false>(IP[(st - 1) & 3], 52, e1y, e1q);
            r1a = r1b; r1b = r1c; r1c = a1;
            if (st >= 3) {
                float4 e1 = vop<false>(vop<false>(r1a, r1b), r1c);
                e1 = maskq(e1, bx - 3 + e1q * 4, by - 2 + e1y, bz - 5 + st, INFINITY);
                *(float4*)&E1[st % 5][e1y * 44 + e1q * 4] = e1;
            }
        }
        // 2b. E2: A2 = xy-min of E1 plane (st-1); write plane bz-7+st (mask -inf; next is dilate)
        if (e2id >= 0 && st >= 4 && st <= 19) {
            float4 a2 = xy3<false>(E1[(st - 1) % 5], 44, e2y, e2q);
            r2a = r2b; r2b = r2c; r2c = a2;
            if (st >= 6) {
                float4 e2 = vop<false>(vop<false>(r2a, r2b), r2c);
                e2 = maskq(e2, bx - 2 + e2q * 4, by - 1 + e2y, bz - 7 + st, -INFINITY);
                *(float4*)&E2[st & 3][e2y * 36 + e2q * 4] = e2;
            }
        }
        // 2c. D: A3 = xy-max of E2 plane (st-1); output zd = bz-9+st
        if (did >= 0 && st >= 7 && st <= 20) {
            float4 a3 = xy3b<true>(E2[(st - 1) & 3], 36, dyy, dq);
            r3a = r3b; r3b = r3c; r3c = a3;
            if (st >= 9) {
                float4 D = vop<true>(vop<true>(r3a, r3b), r3c);
                const float* ar = &E1[(st - 4) % 5][(dyy + 2) * 44 + dq * 4];
                float4 P = ldf4(ar), Q = ldf4(ar + 4);
                float4 av = mk4(P.w, Q.x, Q.y, Q.z);   // E1 (= img_next) at x offset +3
                const int zd = bz - 9 + st;
                size_t gi = (size_t)vol * N_ELEM + ((size_t)zd * DIMH + (by + dyy)) * DIMW + bx + dq * 4;
                float4 dl = mk4(fmaxf(av.x - D.x, 0.f), fmaxf(av.y - D.y, 0.f),
                                fmaxf(av.z - D.z, 0.f), fmaxf(av.w - D.w, 0.f));
                float4 sk = ldf4(skel + gi);
                sk.x += fmaxf(dl.x - sk.x * dl.x, 0.f);
                sk.y += fmaxf(dl.y - sk.y * dl.y, 0.f);
                sk.z += fmaxf(dl.z - sk.z * dl.z, 0.f);
                sk.w += fmaxf(dl.w - sk.w * dl.w, 0.f);
                *(float4*)(skel + gi) = sk;
                *(float4*)(dimg + gi) = av;
            }
        }
        // 3. commit loaded plane to IP ring
        if (st < 18) {
            float* dp = IP[st & 3];
            #pragma unroll
            for (int k = 0; k < 4; ++k) if (fok[k]) dp[loff[k]] = lv[k];
        }
        __syncthreads();
    }
}

// -------- reductions --------
__device__ __forceinline__ double wave_block_reduce(double v, double* red4) {
    for (int off = 32; off > 0; off >>= 1) v += __shfl_down(v, off, 64);
    int wid = threadIdx.x >> 6, lane = threadIdx.x & 63;
    if (lane == 0) red4[wid] = v;
    __syncthreads();
    double r = red4[0] + red4[1] + red4[2] + red4[3];
    __syncthreads();
    return r;
}

// 0: skel_pred*y_true  1: skel_pred  2: skel_true*s2  3: skel_true
// 4: w*s1*y_true       5: w*s1       6: w*y_true      (w = exp(-skel_true^2/2))
// 7: s1*y_true         8: s1         9: y_true
__global__ __launch_bounds__(256) void reduce_partial(const float* __restrict__ yp,
                                                      const float* __restrict__ yt,
                                                      const float* __restrict__ sp,
                                                      const float* __restrict__ st,
                                                      double* __restrict__ partials) {
    double acc[10];
    #pragma unroll
    for (int k = 0; k < 10; ++k) acc[k] = 0.0;

    for (int i = blockIdx.x * 256 + threadIdx.x; i < N4; i += RBLOCKS * 256) {
        float4 x = ldf4(yp + i * 4);
        float4 t = ldf4(yt + i * 4);
        float4 a = ldf4(sp + i * 4);
        float4 b = ldf4(st + i * 4);
        #pragma unroll
        for (int c = 0; c < 4; ++c) {
            float xc = (&x.x)[c], tc = (&t.x)[c], ac = (&a.x)[c], bc = (&b.x)[c];
            float s1 = sigmoidf_(xc);
            float s2 = sigmoidf_(s1);
            float w  = expf(-0.5f * bc * bc);
            acc[0] += (double)(ac * tc);
            acc[1] += (double)ac;
            acc[2] += (double)(bc * s2);
            acc[3] += (double)bc;
            acc[4] += (double)(w * s1 * tc);
            acc[5] += (double)(w * s1);
            acc[6] += (double)(w * tc);
            acc[7] += (double)(s1 * tc);
            acc[8] += (double)s1;
            acc[9] += (double)tc;
        }
    }

    __shared__ double red4[4];
    #pragma unroll
    for (int k = 0; k < 10; ++k) {
        double r = wave_block_reduce(acc[k], red4);
        if (threadIdx.x == 0) partials[blockIdx.x * 10 + k] = r;
        __syncthreads();
    }
}

__global__ __launch_bounds__(256) void finalize_kernel(const double* __restrict__ partials,
                                                       float* __restrict__ out) {
    __shared__ double sums[10];
    __shared__ double red4[4];
    for (int k = 0; k < 10; ++k) {
        double v = 0.0;
        for (int j = threadIdx.x; j < RBLOCKS; j += 256) v += partials[j * 10 + k];
        double r = wave_block_reduce(v, red4);
        if (threadIdx.x == 0) sums[k] = r;
        __syncthreads();
    }
    if (threadIdx.x == 0) {
        double tprec = (sums[0] + 1.0) / (sums[1] + 1.0);
        double tsens = (sums[2] + 1.0) / (sums[3] + 1.0);
        double cldice = 1.0 - 2.0 * (tprec * tsens) / (tprec + tsens + 1.0);
        double boundary = 1.0 - (2.0 * sums[4] + 1.0) / (sums[5] + sums[6] + 1.0);
        double dice = 1.0 - (2.0 * sums[7] + 1.0) / (sums[8] + sums[9] + 1.0);
        out[0] = (float)(0.5 * cldice + 0.3 * boundary + 0.2 * dice);
    }
}

extern "C" void kernel_launch(void* const* d_in, const int* in_sizes, int n_in,
                              void* d_out, int out_size, void* d_ws, size_t ws_size,
                              hipStream_t stream) {
    const float* y_pred = (const float*)d_in[0];
    const float* y_true = (const float*)d_in[1];
    float* out = (float*)d_out;

    const size_t NB = (size_t)2 * N_ELEM;
    float* imgA = (float*)d_ws;
    float* imgB = imgA + NB;
    float* skel = imgB + NB;
    double* partials = (double*)(skel + NB);

    dim3 g(DIMW / 32, DIMH / 16, 8 * 2);   // (4, 8, 16); z = vol*8 + zchunk(12 deep)
    dim3 b(256);

    prologue_kernel<<<(N4 + 255) / 256, 256, 0, stream>>>(y_pred, y_true, imgA);
    init_kernel<<<g, b, 0, stream>>>(imgA, skel);

    float* cur = imgA;
    float* nxt = imgB;
    for (int it = 0; it < 16; ++it) {
        iter_kernel<<<g, b, 0, stream>>>(cur, nxt, skel);
        float* tmp = cur; cur = nxt; nxt = tmp;
    }

    reduce_partial<<<RBLOCKS, 256, 0, stream>>>(y_pred, y_true, skel, skel + N_ELEM, partials);
    finalize_kernel<<<1, 256, 0, stream>>>(partials, out);
}

// Round 8
// 424.980 us; speedup vs baseline: 1.5522x; 1.0109x over previous
//
#include <hip/hip_runtime.h>
#include <math.h>

// Volume geometry (1,1,96,128,128)
#define DIMD 96
#define DIMH 128
#define DIMW 128
#define N_ELEM (DIMD*DIMH*DIMW)   // 1,572,864
#define N4 (N_ELEM/4)

#define RBLOCKS 512

__device__ __forceinline__ float sigmoidf_(float x) { return 1.0f / (1.0f + expf(-x)); }
__device__ __forceinline__ float4 mk4(float a, float b, float c, float d) {
    float4 r; r.x = a; r.y = b; r.z = c; r.w = d; return r;
}
__device__ __forceinline__ float4 ldf4(const float* p) { return *(const float4*)p; }

// Barrier WITHOUT vmcnt drain: LDS producer->consumer fence only.
// Register-destined global loads stay in flight across it (the whole point).
__device__ __forceinline__ void pipe_barrier() {
    asm volatile("s_waitcnt lgkmcnt(0)" ::: "memory");
    __builtin_amdgcn_s_barrier();
    asm volatile("" ::: "memory");
}

template<bool MX> __device__ __forceinline__ float op2(float a, float b) {
    return MX ? fmaxf(a, b) : fminf(a, b);
}
template<bool MX> __device__ __forceinline__ float op3(float a, float b, float c) {
    return op2<MX>(op2<MX>(a, b), c);   // -> v_min3/v_max3
}
template<bool MX> __device__ __forceinline__ float4 vop(float4 a, float4 b) {
    return mk4(op2<MX>(a.x,b.x), op2<MX>(a.y,b.y), op2<MX>(a.z,b.z), op2<MX>(a.w,b.w));
}
// out[i] = op(v[i..i+2]), v = concat(A,B), window start aligned with quad
template<bool MX> __device__ __forceinline__ float4 shift3(float4 A, float4 B) {
    return mk4(op3<MX>(A.x,A.y,A.z), op3<MX>(A.y,A.z,A.w),
               op3<MX>(A.z,A.w,B.x), op3<MX>(A.w,B.x,B.y));
}
// window start offset +1 within the quad pair
template<bool MX> __device__ __forceinline__ float4 shift3b(float4 A, float4 B) {
    return mk4(op3<MX>(A.y,A.z,A.w), op3<MX>(A.z,A.w,B.x),
               op3<MX>(A.w,B.x,B.y), op3<MX>(B.x,B.y,B.z));
}
template<bool MX> __device__ __forceinline__ float4 xy3(const float* base, int stride, int y, int xq) {
    float4 acc;
    #pragma unroll
    for (int dy = 0; dy < 3; ++dy) {
        const float* row = base + (y + dy) * stride + xq * 4;
        float4 m = shift3<MX>(ldf4(row), ldf4(row + 4));
        acc = dy ? vop<MX>(acc, m) : m;
    }
    return acc;
}
template<bool MX> __device__ __forceinline__ float4 xy3b(const float* base, int stride, int y, int xq) {
    float4 acc;
    #pragma unroll
    for (int dy = 0; dy < 3; ++dy) {
        const float* row = base + (y + dy) * stride + xq * 4;
        float4 m = shift3b<MX>(ldf4(row), ldf4(row + 4));
        acc = dy ? vop<MX>(acc, m) : m;
    }
    return acc;
}
__device__ __forceinline__ float4 maskq(float4 v, int gx0, int gy, int gz, float NEUT) {
    const bool okzy = ((unsigned)gz < DIMD) & ((unsigned)gy < DIMH);
    float4 r;
    r.x = (okzy & ((unsigned)(gx0 + 0) < DIMW)) ? v.x : NEUT;
    r.y = (okzy & ((unsigned)(gx0 + 1) < DIMW)) ? v.y : NEUT;
    r.z = (okzy & ((unsigned)(gx0 + 2) < DIMW)) ? v.z : NEUT;
    r.w = (okzy & ((unsigned)(gx0 + 3) < DIMW)) ? v.w : NEUT;
    return r;
}

// -------- prologue --------
__global__ __launch_bounds__(256) void prologue_kernel(const float* __restrict__ yp,
                                                       const float* __restrict__ yt,
                                                       float* __restrict__ img) {
    int i = blockIdx.x * 256 + threadIdx.x;
    if (i < N4) {
        float4 a = ldf4(yp + i * 4);
        float4 b = ldf4(yt + i * 4);
        float4 s = mk4(sigmoidf_(sigmoidf_(a.x)), sigmoidf_(sigmoidf_(a.y)),
                       sigmoidf_(sigmoidf_(a.z)), sigmoidf_(sigmoidf_(a.w)));
        *(float4*)(img + i * 4) = s;
        *(float4*)(img + N_ELEM + i * 4) = b;
    }
}

// -------- init: skel = relu(img - dilate(erode(img))) --------
// Skewed single-barrier pipeline + 2-step register prefetch, tile 32x16, z-chunk 12.
__global__ __launch_bounds__(256) void init_kernel(const float* __restrict__ img,
                                                   float* __restrict__ skel) {
    __shared__ alignas(16) float IP[5][20 * 44];  // origin (bx-2, by-2), used 40 wide
    __shared__ alignas(16) float E1[4][18 * 36];  // origin (bx-1, by-1)
    const int tid = threadIdx.x;
    const int vol = blockIdx.z >> 3, zc = blockIdx.z & 7;
    const int bx = blockIdx.x * 32, by = blockIdx.y * 16, bz = zc * 12;
    const float* s = img + (size_t)vol * N_ELEM;

    const int e1id = (tid < 162) ? tid : -1;                         // 9q x 18r
    const int did  = (tid >= 162) ? tid - 162 : (tid < 34 ? tid + 94 : -1);  // 8q x 16r
    const int e1q = (e1id >= 0) ? e1id % 9 : 0, e1y = (e1id >= 0) ? e1id / 9 : 0;
    const int dq  = (did  >= 0) ? (did & 7) : 0, dyy = (did >= 0) ? (did >> 3) : 0;

    // precompute load offsets (20x40 = 800 elems)
    int goff[4], loff[4]; bool fok[4];
    #pragma unroll
    for (int k = 0; k < 4; ++k) {
        int f = tid + k * 256;
        fok[k] = f < 800;
        int ly = f / 40, lx = f - ly * 40;
        int gy = min(max(by - 2 + ly, 0), DIMH - 1);
        int gx = min(max(bx - 2 + lx, 0), DIMW - 1);
        goff[k] = fok[k] ? gy * DIMW + gx : 0;
        loff[k] = ly * 44 + lx;
    }

    float4 r1a{}, r1b{}, r1c{}, r2a{}, r2b{}, r2c{};
    float lvA[4], lvB[4];

    auto issue = [&](int p, float (&lv)[4]) {
        const int zcl = min(max(bz - 2 + p, 0), DIMD - 1);
        const float* sp = s + (size_t)zcl * DIMH * DIMW;
        #pragma unroll
        for (int k = 0; k < 4; ++k) lv[k] = sp[goff[k]];
    };
    auto commit = [&](const float (&lv)[4], float* dp) {
        #pragma unroll
        for (int k = 0; k < 4; ++k) if (fok[k]) dp[loff[k]] = lv[k];
    };
    auto stages = [&](int st) {
        // E1 stage: A1 = xy-min of IP plane (st-1); E1 plane bz-4+st (mask -inf; next is dilate)
        if (e1id >= 0 && st >= 1 && st <= 16) {
            float4 a1 = xy3<false>(IP[(st - 1) % 5], 44, e1y, e1q);
            r1a = r1b; r1b = r1c; r1c = a1;
            if (st >= 3) {
                float4 e1 = vop<false>(vop<false>(r1a, r1b), r1c);
                e1 = maskq(e1, bx - 1 + e1q * 4, by - 1 + e1y, bz - 4 + st, -INFINITY);
                *(float4*)&E1[st & 3][e1y * 36 + e1q * 4] = e1;
            }
        }
        // D stage: A2 = xy-max of E1 plane (st-1); D center zd = bz-6+st
        if (did >= 0 && st >= 4 && st <= 17) {
            float4 a2 = xy3<true>(E1[(st - 1) & 3], 36, dyy, dq);
            r2a = r2b; r2b = r2c; r2c = a2;
            if (st >= 6) {
                float4 D = vop<true>(vop<true>(r2a, r2b), r2c);
                const float* ar = &IP[(st - 4) % 5][(dyy + 2) * 44 + dq * 4];
                float4 P = ldf4(ar), Q = ldf4(ar + 4);
                float4 av = mk4(P.z, P.w, Q.x, Q.y);   // img at x offset +2
                const int zd = bz - 6 + st;
                size_t gi = (size_t)vol * N_ELEM + ((size_t)zd * DIMH + (by + dyy)) * DIMW + bx + dq * 4;
                float4 dl = mk4(fmaxf(av.x - D.x, 0.f), fmaxf(av.y - D.y, 0.f),
                                fmaxf(av.z - D.z, 0.f), fmaxf(av.w - D.w, 0.f));
                *(float4*)(skel + gi) = dl;
            }
        }
    };

    issue(0, lvA);
    issue(1, lvB);
    for (int st = 0; st < 18; st += 2) {
        if (st < 16) commit(lvA, IP[st % 5]);
        if (st + 2 < 16) issue(st + 2, lvA);
        stages(st);
        pipe_barrier();
        const int s1 = st + 1;
        if (s1 < 16) commit(lvB, IP[s1 % 5]);
        if (s1 + 2 < 16) issue(s1 + 2, lvB);
        stages(s1);
        pipe_barrier();
    }
}

// -------- fused iteration, skewed single-barrier pipeline + 2-step prefetch --------
// img_next = erode(img); open = dilate(erode(img_next)); delta = relu(img_next - open);
// skel += relu(delta - skel*delta); dimg = img_next
// tile 32x16, z-chunk 12, 21 steps. G(st)=bz-3+st (st<18).
__global__ __launch_bounds__(256) void iter_kernel(const float* __restrict__ src,
                                                   float* __restrict__ dimg,
                                                   float* __restrict__ skel) {
    __shared__ alignas(16) float IP[4][22 * 52];  // origin (bx-4, by-3), used 44 wide
    __shared__ alignas(16) float E1[5][20 * 44];  // origin (bx-3, by-2), used 40 wide
    __shared__ alignas(16) float E2[4][18 * 36];  // origin (bx-2, by-1)
    const int tid = threadIdx.x;
    const int vol = blockIdx.z >> 3, zc = blockIdx.z & 7;
    const int bx = blockIdx.x * 32, by = blockIdx.y * 16, bz = zc * 12;
    const float* s = src + (size_t)vol * N_ELEM;

    // task decode: E1 200 tasks (10q x 20r), E2 162 (9q x 18r), D 128 (8q x 16r); <=2 per thread
    const int e1id = (tid < 200) ? tid : -1;
    const int e2id = (tid >= 200) ? (tid - 200) : (tid < 106 ? tid + 56 : -1);
    const int did  = (tid >= 106 && tid < 234) ? (tid - 106) : -1;
    const int e1q = (e1id >= 0) ? e1id % 10 : 0, e1y = (e1id >= 0) ? e1id / 10 : 0;
    const int e2q = (e2id >= 0) ? e2id % 9  : 0, e2y = (e2id >= 0) ? e2id / 9  : 0;
    const int dq  = (did  >= 0) ? (did & 7) : 0, dyy = (did >= 0) ? (did >> 3) : 0;

    // precompute load offsets (22x44 = 968 elems)
    int goff[4], loff[4]; bool fok[4];
    #pragma unroll
    for (int k = 0; k < 4; ++k) {
        int f = tid + k * 256;
        fok[k] = f < 968;
        int ly = f / 44, lx = f - ly * 44;
        int gy = min(max(by - 3 + ly, 0), DIMH - 1);
        int gx = min(max(bx - 4 + lx, 0), DIMW - 1);
        goff[k] = fok[k] ? gy * DIMW + gx : 0;
        loff[k] = ly * 52 + lx;
    }

    float4 r1a{}, r1b{}, r1c{}, r2a{}, r2b{}, r2c{}, r3a{}, r3b{}, r3c{};
    float lvA[4], lvB[4];

    auto issue = [&](int p, float (&lv)[4]) {
        const int zcl = min(max(bz - 3 + p, 0), DIMD - 1);
        const float* sp = s + (size_t)zcl * DIMH * DIMW;
        #pragma unroll
        for (int k = 0; k < 4; ++k) lv[k] = sp[goff[k]];
    };
    auto commit = [&](const float (&lv)[4], float* dp) {
        #pragma unroll
        for (int k = 0; k < 4; ++k) if (fok[k]) dp[loff[k]] = lv[k];
    };
    auto stages = [&](int st) {
        // E1: A1 = xy-min of IP plane (st-1); write plane bz-5+st (mask +inf; next is erode)
        if (e1id >= 0 && st >= 1 && st <= 18) {
            float4 a1 = xy3<false>(IP[(st - 1) & 3], 52, e1y, e1q);
            r1a = r1b; r1b = r1c; r1c = a1;
            if (st >= 3) {
                float4 e1 = vop<false>(vop<false>(r1a, r1b), r1c);
                e1 = maskq(e1, bx - 3 + e1q * 4, by - 2 + e1y, bz - 5 + st, INFINITY);
                *(float4*)&E1[st % 5][e1y * 44 + e1q * 4] = e1;
            }
        }
        // E2: A2 = xy-min of E1 plane (st-1); write plane bz-7+st (mask -inf; next is dilate)
        if (e2id >= 0 && st >= 4 && st <= 19) {
            float4 a2 = xy3<false>(E1[(st - 1) % 5], 44, e2y, e2q);
            r2a = r2b; r2b = r2c; r2c = a2;
            if (st >= 6) {
                float4 e2 = vop<false>(vop<false>(r2a, r2b), r2c);
                e2 = maskq(e2, bx - 2 + e2q * 4, by - 1 + e2y, bz - 7 + st, -INFINITY);
                *(float4*)&E2[st & 3][e2y * 36 + e2q * 4] = e2;
            }
        }
        // D: A3 = xy-max of E2 plane (st-1); output zd = bz-9+st
        if (did >= 0 && st >= 7 && st <= 20) {
            float4 a3 = xy3b<true>(E2[(st - 1) & 3], 36, dyy, dq);
            r3a = r3b; r3b = r3c; r3c = a3;
            if (st >= 9) {
                float4 D = vop<true>(vop<true>(r3a, r3b), r3c);
                const float* ar = &E1[(st - 4) % 5][(dyy + 2) * 44 + dq * 4];
                float4 P = ldf4(ar), Q = ldf4(ar + 4);
                float4 av = mk4(P.w, Q.x, Q.y, Q.z);   // E1 (= img_next) at x offset +3
                const int zd = bz - 9 + st;
                size_t gi = (size_t)vol * N_ELEM + ((size_t)zd * DIMH + (by + dyy)) * DIMW + bx + dq * 4;
                float4 dl = mk4(fmaxf(av.x - D.x, 0.f), fmaxf(av.y - D.y, 0.f),
                                fmaxf(av.z - D.z, 0.f), fmaxf(av.w - D.w, 0.f));
                float4 sk = ldf4(skel + gi);
                sk.x += fmaxf(dl.x - sk.x * dl.x, 0.f);
                sk.y += fmaxf(dl.y - sk.y * dl.y, 0.f);
                sk.z += fmaxf(dl.z - sk.z * dl.z, 0.f);
                sk.w += fmaxf(dl.w - sk.w * dl.w, 0.f);
                *(float4*)(skel + gi) = sk;
                *(float4*)(dimg + gi) = av;
            }
        }
    };

    issue(0, lvA);
    issue(1, lvB);
    for (int st = 0; st < 21; st += 2) {
        if (st < 18) commit(lvA, IP[st & 3]);
        if (st + 2 < 18) issue(st + 2, lvA);
        stages(st);
        pipe_barrier();
        const int s1 = st + 1;
        if (s1 < 21) {
            if (s1 < 18) commit(lvB, IP[s1 & 3]);
            if (s1 + 2 < 18) issue(s1 + 2, lvB);
            stages(s1);
            pipe_barrier();
        }
    }
}

// -------- reductions --------
__device__ __forceinline__ double wave_block_reduce(double v, double* red4) {
    for (int off = 32; off > 0; off >>= 1) v += __shfl_down(v, off, 64);
    int wid = threadIdx.x >> 6, lane = threadIdx.x & 63;
    if (lane == 0) red4[wid] = v;
    __syncthreads();
    double r = red4[0] + red4[1] + red4[2] + red4[3];
    __syncthreads();
    return r;
}

// 0: skel_pred*y_true  1: skel_pred  2: skel_true*s2  3: skel_true
// 4: w*s1*y_true       5: w*s1       6: w*y_true      (w = exp(-skel_true^2/2))
// 7: s1*y_true         8: s1         9: y_true
__global__ __launch_bounds__(256) void reduce_partial(const float* __restrict__ yp,
                                                      const float* __restrict__ yt,
                                                      const float* __restrict__ sp,
                                                      const float* __restrict__ st,
                                                      double* __restrict__ partials) {
    double acc[10];
    #pragma unroll
    for (int k = 0; k < 10; ++k) acc[k] = 0.0;

    for (int i = blockIdx.x * 256 + threadIdx.x; i < N4; i += RBLOCKS * 256) {
        float4 x = ldf4(yp + i * 4);
        float4 t = ldf4(yt + i * 4);
        float4 a = ldf4(sp + i * 4);
        float4 b = ldf4(st + i * 4);
        #pragma unroll
        for (int c = 0; c < 4; ++c) {
            float xc = (&x.x)[c], tc = (&t.x)[c], ac = (&a.x)[c], bc = (&b.x)[c];
            float s1 = sigmoidf_(xc);
            float s2 = sigmoidf_(s1);
            float w  = expf(-0.5f * bc * bc);
            acc[0] += (double)(ac * tc);
            acc[1] += (double)ac;
            acc[2] += (double)(bc * s2);
            acc[3] += (double)bc;
            acc[4] += (double)(w * s1 * tc);
            acc[5] += (double)(w * s1);
            acc[6] += (double)(w * tc);
            acc[7] += (double)(s1 * tc);
            acc[8] += (double)s1;
            acc[9] += (double)tc;
        }
    }

    __shared__ double red4[4];
    #pragma unroll
    for (int k = 0; k < 10; ++k) {
        double r = wave_block_reduce(acc[k], red4);
        if (threadIdx.x == 0) partials[blockIdx.x * 10 + k] = r;
        __syncthreads();
    }
}

__global__ __launch_bounds__(256) void finalize_kernel(const double* __restrict__ partials,
                                                       float* __restrict__ out) {
    __shared__ double sums[10];
    __shared__ double red4[4];
    for (int k = 0; k < 10; ++k) {
        double v = 0.0;
        for (int j = threadIdx.x; j < RBLOCKS; j += 256) v += partials[j * 10 + k];
        double r = wave_block_reduce(v, red4);
        if (threadIdx.x == 0) sums[k] = r;
        __syncthreads();
    }
    if (threadIdx.x == 0) {
        double tprec = (sums[0] + 1.0) / (sums[1] + 1.0);
        double tsens = (sums[2] + 1.0) / (sums[3] + 1.0);
        double cldice = 1.0 - 2.0 * (tprec * tsens) / (tprec + tsens + 1.0);
        double boundary = 1.0 - (2.0 * sums[4] + 1.0) / (sums[5] + sums[6] + 1.0);
        double dice = 1.0 - (2.0 * sums[7] + 1.0) / (sums[8] + sums[9] + 1.0);
        out[0] = (float)(0.5 * cldice + 0.3 * boundary + 0.2 * dice);
    }
}

extern "C" void kernel_launch(void* const* d_in, const int* in_sizes, int n_in,
                              void* d_out, int out_size, void* d_ws, size_t ws_size,
                              hipStream_t stream) {
    const float* y_pred = (const float*)d_in[0];
    const float* y_true = (const float*)d_in[1];
    float* out = (float*)d_out;

    const size_t NB = (size_t)2 * N_ELEM;
    float* imgA = (float*)d_ws;
    float* imgB = imgA + NB;
    float* skel = imgB + NB;
    double* partials = (double*)(skel + NB);

    dim3 g(DIMW / 32, DIMH / 16, 8 * 2);   // (4, 8, 16); z = vol*8 + zchunk(12 deep)
    dim3 b(256);

    prologue_kernel<<<(N4 + 255) / 256, 256, 0, stream>>>(y_pred, y_true, imgA);
    init_kernel<<<g, b, 0, stream>>>(imgA, skel);

    float* cur = imgA;
    float* nxt = imgB;
    for (int it = 0; it < 16; ++it) {
        iter_kernel<<<g, b, 0, stream>>>(cur, nxt, skel);
        float* tmp = cur; cur = nxt; nxt = tmp;
    }

    reduce_partial<<<RBLOCKS, 256, 0, stream>>>(y_pred, y_true, skel, skel + N_ELEM, partials);
    finalize_kernel<<<1, 256, 0, stream>>>(partials, out);
}

// Round 9
// 327.890 us; speedup vs baseline: 2.0118x; 1.2961x over previous
//
#include <hip/hip_runtime.h>
#include <math.h>

// Volume geometry (1,1,96,128,128)
#define DIMD 96
#define DIMH 128
#define DIMW 128
#define N_ELEM (DIMD*DIMH*DIMW)   // 1,572,864
#define N4 (N_ELEM/4)

#define RBLOCKS 512

__device__ __forceinline__ float sigmoidf_(float x) { return 1.0f / (1.0f + expf(-x)); }
__device__ __forceinline__ float4 mk4(float a, float b, float c, float d) {
    float4 r; r.x = a; r.y = b; r.z = c; r.w = d; return r;
}
__device__ __forceinline__ float4 ldf4(const float* p) { return *(const float4*)p; }

// Barrier WITHOUT vmcnt drain: LDS producer->consumer fence only.
__device__ __forceinline__ void pipe_barrier() {
    asm volatile("s_waitcnt lgkmcnt(0)" ::: "memory");
    __builtin_amdgcn_s_barrier();
    asm volatile("" ::: "memory");
}

template<bool MX> __device__ __forceinline__ float op2(float a, float b) {
    return MX ? fmaxf(a, b) : fminf(a, b);
}
template<bool MX> __device__ __forceinline__ float op3(float a, float b, float c) {
    return op2<MX>(op2<MX>(a, b), c);   // -> v_min3/v_max3
}
template<bool MX> __device__ __forceinline__ float4 vop(float4 a, float4 b) {
    return mk4(op2<MX>(a.x,b.x), op2<MX>(a.y,b.y), op2<MX>(a.z,b.z), op2<MX>(a.w,b.w));
}
// out[i] = op(v[i..i+2]), v = concat(A,B), window start aligned with quad
template<bool MX> __device__ __forceinline__ float4 shift3(float4 A, float4 B) {
    return mk4(op3<MX>(A.x,A.y,A.z), op3<MX>(A.y,A.z,A.w),
               op3<MX>(A.z,A.w,B.x), op3<MX>(A.w,B.x,B.y));
}
template<bool MX> __device__ __forceinline__ float4 xy3(const float* base, int stride, int y, int xq) {
    float4 acc;
    #pragma unroll
    for (int dy = 0; dy < 3; ++dy) {
        const float* row = base + (y + dy) * stride + xq * 4;
        float4 m = shift3<MX>(ldf4(row), ldf4(row + 4));
        acc = dy ? vop<MX>(acc, m) : m;
    }
    return acc;
}
__device__ __forceinline__ float4 maskq(float4 v, int gx0, int gy, int gz, float NEUT) {
    const bool okzy = ((unsigned)gz < DIMD) & ((unsigned)gy < DIMH);
    float4 r;
    r.x = (okzy & ((unsigned)(gx0 + 0) < DIMW)) ? v.x : NEUT;
    r.y = (okzy & ((unsigned)(gx0 + 1) < DIMW)) ? v.y : NEUT;
    r.z = (okzy & ((unsigned)(gx0 + 2) < DIMW)) ? v.z : NEUT;
    r.w = (okzy & ((unsigned)(gx0 + 3) < DIMW)) ? v.w : NEUT;
    return r;
}

// -------- prologue --------
__global__ __launch_bounds__(256) void prologue_kernel(const float* __restrict__ yp,
                                                       const float* __restrict__ yt,
                                                       float* __restrict__ img) {
    int i = blockIdx.x * 256 + threadIdx.x;
    if (i < N4) {
        float4 a = ldf4(yp + i * 4);
        float4 b = ldf4(yt + i * 4);
        float4 s = mk4(sigmoidf_(sigmoidf_(a.x)), sigmoidf_(sigmoidf_(a.y)),
                       sigmoidf_(sigmoidf_(a.z)), sigmoidf_(sigmoidf_(a.w)));
        *(float4*)(img + i * 4) = s;
        *(float4*)(img + N_ELEM + i * 4) = b;
    }
}

// -------- unified 2-stage morphology kernel --------
// Input V. E = erode(V) (stored to eout, interior), D = dilate(E),
// delta = relu(V - D);  EPI 1: skel = delta;  EPI 2: skel += relu(delta - skel*delta).
// Chain identity: with V = I_{m+1}, eout = I_{m+2} and delta is iteration m's delta.
// Tile 32x8, z-chunk 12, skewed single-barrier pipeline, 18 steps.
// Skew: load G(st)=bz-2+st (st<16) -> IP[st%5];
//   E stage: xy-min of IP[(st-1)%5], z-ring -> E[st&3], center z bz-4+st, st in [3,16], mask -inf
//   D stage: xy-max of E[(st-1)&3], z-ring -> output zd = bz-6+st, st in [6,17];
//            aux V from IP[(st-4)%5]; eout value from E[(st-2)&3].
template<int EPI>
__global__ __launch_bounds__(256) void morph_kernel(const float* __restrict__ V,
                                                    float* __restrict__ eout,
                                                    float* __restrict__ skel) {
    __shared__ alignas(16) float IP[5][12 * 40];  // V planes, origin (bx-2, by-2), used 38 wide
    __shared__ alignas(16) float E[4][10 * 36];   // erode planes, origin (bx-1, by-1)
    const int tid = threadIdx.x;
    const int vol = blockIdx.z >> 3, zc = blockIdx.z & 7;
    const int bx = blockIdx.x * 32, by = blockIdx.y * 8, bz = zc * 12;
    const float* s = V + (size_t)vol * N_ELEM;

    // tasks: E = 90 (9q x 10r) on tid 0..89; D = 64 (8q x 8r) on wave 2 (tid 128..191)
    const int eid = (tid < 90) ? tid : -1;
    const int did = (tid >= 128 && tid < 192) ? tid - 128 : -1;
    const int eq = (eid >= 0) ? eid % 9 : 0, ey = (eid >= 0) ? eid / 9 : 0;
    const int dq = (did >= 0) ? (did & 7) : 0, dyy = (did >= 0) ? (did >> 3) : 0;

    // load offsets: 12 rows x 38 cols = 456 elems, <=2 per thread
    int goff[2], loff[2]; bool fok[2];
    #pragma unroll
    for (int k = 0; k < 2; ++k) {
        int f = tid + k * 256;
        fok[k] = f < 456;
        int ly = f / 38, lx = f - ly * 38;
        int gy = min(max(by - 2 + ly, 0), DIMH - 1);
        int gx = min(max(bx - 2 + lx, 0), DIMW - 1);
        goff[k] = fok[k] ? gy * DIMW + gx : 0;
        loff[k] = ly * 40 + lx;
    }

    float4 r1a{}, r1b{}, r1c{}, r2a{}, r2b{}, r2c{};
    float lvA[2], lvB[2];
    float4 skA{}, skB{};

    auto issue = [&](int p, float (&lv)[2]) {
        const int zcl = min(max(bz - 2 + p, 0), DIMD - 1);
        const float* sp = s + (size_t)zcl * DIMH * DIMW;
        #pragma unroll
        for (int k = 0; k < 2; ++k) lv[k] = sp[goff[k]];
    };
    auto commit = [&](const float (&lv)[2], float* dp) {
        #pragma unroll
        for (int k = 0; k < 2; ++k) if (fok[k]) dp[loff[k]] = lv[k];
    };
    auto sk_gi = [&](int st) -> size_t {
        const int zd = bz - 6 + st;
        return (size_t)vol * N_ELEM + ((size_t)zd * DIMH + (by + dyy)) * DIMW + bx + dq * 4;
    };
    auto issue_sk = [&](int st, float4& r) {
        if (EPI == 2 && did >= 0 && st >= 6 && st <= 17) r = ldf4(skel + sk_gi(st));
    };
    auto stages = [&](int st, const float4& sk4) {
        // E: xy-min of IP plane G(st-1); z-ring; write E plane bz-4+st (mask -inf; next dilate)
        if (eid >= 0 && st >= 1 && st <= 16) {
            float4 a1 = xy3<false>(IP[(st - 1) % 5], 40, ey, eq);
            r1a = r1b; r1b = r1c; r1c = a1;
            if (st >= 3) {
                float4 e1 = vop<false>(vop<false>(r1a, r1b), r1c);
                e1 = maskq(e1, bx - 1 + eq * 4, by - 1 + ey, bz - 4 + st, -INFINITY);
                *(float4*)&E[st & 3][ey * 36 + eq * 4] = e1;
            }
        }
        // D: xy-max of E plane (st-1); z-ring; epilogue at zd = bz-6+st
        if (did >= 0 && st >= 4 && st <= 17) {
            float4 a2 = xy3<true>(E[(st - 1) & 3], 36, dyy, dq);
            r2a = r2b; r2b = r2c; r2c = a2;
            if (st >= 6) {
                float4 D = vop<true>(vop<true>(r2a, r2b), r2c);
                // aux = V at output position: IP origin (bx-2,by-2) -> row dyy+2, x offset +2
                const float* ar = &IP[(st - 4) % 5][(dyy + 2) * 40 + dq * 4];
                float4 P = ldf4(ar), Q = ldf4(ar + 4);
                float4 av = mk4(P.z, P.w, Q.x, Q.y);
                // eout value = E at output position: E origin (bx-1,by-1) -> row dyy+1, x offset +1
                const float* er = &E[(st - 2) & 3][(dyy + 1) * 36 + dq * 4];
                float4 R = ldf4(er), S = ldf4(er + 4);
                float4 ev = mk4(R.y, R.z, R.w, S.x);
                const size_t gi = sk_gi(st);
                float4 dl = mk4(fmaxf(av.x - D.x, 0.f), fmaxf(av.y - D.y, 0.f),
                                fmaxf(av.z - D.z, 0.f), fmaxf(av.w - D.w, 0.f));
                if (EPI == 1) {
                    *(float4*)(skel + gi) = dl;
                } else {
                    float4 sk = sk4;
                    sk.x += fmaxf(dl.x - sk.x * dl.x, 0.f);
                    sk.y += fmaxf(dl.y - sk.y * dl.y, 0.f);
                    sk.z += fmaxf(dl.z - sk.z * dl.z, 0.f);
                    sk.w += fmaxf(dl.w - sk.w * dl.w, 0.f);
                    *(float4*)(skel + gi) = sk;
                }
                *(float4*)(eout + gi) = ev;
            }
        }
    };

    issue(0, lvA);
    issue(1, lvB);
    issue_sk(6, skA);   // even steps consume skA
    issue_sk(7, skB);   // odd steps consume skB
    for (int st = 0; st < 18; st += 2) {
        if (st < 16) commit(lvA, IP[st % 5]);
        if (st + 2 < 16) issue(st + 2, lvA);
        stages(st, skA);
        issue_sk(st + 2, skA);
        pipe_barrier();
        const int s1 = st + 1;
        if (s1 < 16) commit(lvB, IP[s1 % 5]);
        if (s1 + 2 < 16) issue(s1 + 2, lvB);
        stages(s1, skB);
        issue_sk(s1 + 2, skB);
        pipe_barrier();
    }
}

// -------- reductions --------
__device__ __forceinline__ double wave_block_reduce(double v, double* red4) {
    for (int off = 32; off > 0; off >>= 1) v += __shfl_down(v, off, 64);
    int wid = threadIdx.x >> 6, lane = threadIdx.x & 63;
    if (lane == 0) red4[wid] = v;
    __syncthreads();
    double r = red4[0] + red4[1] + red4[2] + red4[3];
    __syncthreads();
    return r;
}

// 0: skel_pred*y_true  1: skel_pred  2: skel_true*s2  3: skel_true
// 4: w*s1*y_true       5: w*s1       6: w*y_true      (w = exp(-skel_true^2/2))
// 7: s1*y_true         8: s1         9: y_true
__global__ __launch_bounds__(256) void reduce_partial(const float* __restrict__ yp,
                                                      const float* __restrict__ yt,
                                                      const float* __restrict__ sp,
                                                      const float* __restrict__ st,
                                                      double* __restrict__ partials) {
    double acc[10];
    #pragma unroll
    for (int k = 0; k < 10; ++k) acc[k] = 0.0;

    for (int i = blockIdx.x * 256 + threadIdx.x; i < N4; i += RBLOCKS * 256) {
        float4 x = ldf4(yp + i * 4);
        float4 t = ldf4(yt + i * 4);
        float4 a = ldf4(sp + i * 4);
        float4 b = ldf4(st + i * 4);
        #pragma unroll
        for (int c = 0; c < 4; ++c) {
            float xc = (&x.x)[c], tc = (&t.x)[c], ac = (&a.x)[c], bc = (&b.x)[c];
            float s1 = sigmoidf_(xc);
            float s2 = sigmoidf_(s1);
            float w  = expf(-0.5f * bc * bc);
            acc[0] += (double)(ac * tc);
            acc[1] += (double)ac;
            acc[2] += (double)(bc * s2);
            acc[3] += (double)bc;
            acc[4] += (double)(w * s1 * tc);
            acc[5] += (double)(w * s1);
            acc[6] += (double)(w * tc);
            acc[7] += (double)(s1 * tc);
            acc[8] += (double)s1;
            acc[9] += (double)tc;
        }
    }

    __shared__ double red4[4];
    #pragma unroll
    for (int k = 0; k < 10; ++k) {
        double r = wave_block_reduce(acc[k], red4);
        if (threadIdx.x == 0) partials[blockIdx.x * 10 + k] = r;
        __syncthreads();
    }
}

__global__ __launch_bounds__(256) void finalize_kernel(const double* __restrict__ partials,
                                                       float* __restrict__ out) {
    __shared__ double sums[10];
    __shared__ double red4[4];
    for (int k = 0; k < 10; ++k) {
        double v = 0.0;
        for (int j = threadIdx.x; j < RBLOCKS; j += 256) v += partials[j * 10 + k];
        double r = wave_block_reduce(v, red4);
        if (threadIdx.x == 0) sums[k] = r;
        __syncthreads();
    }
    if (threadIdx.x == 0) {
        double tprec = (sums[0] + 1.0) / (sums[1] + 1.0);
        double tsens = (sums[2] + 1.0) / (sums[3] + 1.0);
        double cldice = 1.0 - 2.0 * (tprec * tsens) / (tprec + tsens + 1.0);
        double boundary = 1.0 - (2.0 * sums[4] + 1.0) / (sums[5] + sums[6] + 1.0);
        double dice = 1.0 - (2.0 * sums[7] + 1.0) / (sums[8] + sums[9] + 1.0);
        out[0] = (float)(0.5 * cldice + 0.3 * boundary + 0.2 * dice);
    }
}

extern "C" void kernel_launch(void* const* d_in, const int* in_sizes, int n_in,
                              void* d_out, int out_size, void* d_ws, size_t ws_size,
                              hipStream_t stream) {
    const float* y_pred = (const float*)d_in[0];
    const float* y_true = (const float*)d_in[1];
    float* out = (float*)d_out;

    const size_t NB = (size_t)2 * N_ELEM;
    float* imgA = (float*)d_ws;      // I_m chain buffers (ping-pong)
    float* imgB = imgA + NB;
    float* skel = imgB + NB;
    double* partials = (double*)(skel + NB);

    dim3 g(DIMW / 32, DIMH / 8, 8 * 2);   // (4, 16, 16); z = vol*8 + zchunk(12 deep)
    dim3 b(256);

    prologue_kernel<<<(N4 + 255) / 256, 256, 0, stream>>>(y_pred, y_true, imgA);
    // init: V = I_0, skel = relu(I_0 - dilate(erode(I_0))), eout = I_1
    morph_kernel<1><<<g, b, 0, stream>>>(imgA, imgB, skel);

    float* cur = imgB;   // holds I_{m+1}
    float* nxt = imgA;
    for (int it = 0; it < 16; ++it) {
        // V = I_{m+1}; delta vs dilate(I_{m+2}); eout = I_{m+2}
        morph_kernel<2><<<g, b, 0, stream>>>(cur, nxt, skel);
        float* tmp = cur; cur = nxt; nxt = tmp;
    }

    reduce_partial<<<RBLOCKS, 256, 0, stream>>>(y_pred, y_true, skel, skel + N_ELEM, partials);
    finalize_kernel<<<1, 256, 0, stream>>>(partials, out);
}

// Round 10
// 237.268 us; speedup vs baseline: 2.7802x; 1.3819x over previous
//
#include <hip/hip_runtime.h>
#include <math.h>

// Volume geometry (1,1,96,128,128)
#define DIMD 96
#define DIMH 128
#define DIMW 128
#define N_ELEM (DIMD*DIMH*DIMW)   // 1,572,864
#define N4 (N_ELEM/4)

#define RBLOCKS 512

__device__ __forceinline__ float sigmoidf_(float x) { return 1.0f / (1.0f + expf(-x)); }
__device__ __forceinline__ float4 mk4(float a, float b, float c, float d) {
    float4 r; r.x = a; r.y = b; r.z = c; r.w = d; return r;
}
__device__ __forceinline__ float4 ldf4(const float* p) { return *(const float4*)p; }

// Barrier WITHOUT vmcnt drain: LDS producer->consumer fence only.
__device__ __forceinline__ void pipe_barrier() {
    asm volatile("s_waitcnt lgkmcnt(0)" ::: "memory");
    __builtin_amdgcn_s_barrier();
    asm volatile("" ::: "memory");
}

template<bool MX> __device__ __forceinline__ float op2(float a, float b) {
    return MX ? fmaxf(a, b) : fminf(a, b);
}
template<bool MX> __device__ __forceinline__ float op3(float a, float b, float c) {
    return op2<MX>(op2<MX>(a, b), c);   // -> v_min3/v_max3
}
template<bool MX> __device__ __forceinline__ float4 vop(float4 a, float4 b) {
    return mk4(op2<MX>(a.x,b.x), op2<MX>(a.y,b.y), op2<MX>(a.z,b.z), op2<MX>(a.w,b.w));
}
// window starts at +0 / +1 / +2 within concat(A,B)
template<bool MX> __device__ __forceinline__ float4 shift3(float4 A, float4 B) {
    return mk4(op3<MX>(A.x,A.y,A.z), op3<MX>(A.y,A.z,A.w),
               op3<MX>(A.z,A.w,B.x), op3<MX>(A.w,B.x,B.y));
}
template<bool MX> __device__ __forceinline__ float4 shift3b(float4 A, float4 B) {
    return mk4(op3<MX>(A.y,A.z,A.w), op3<MX>(A.z,A.w,B.x),
               op3<MX>(A.w,B.x,B.y), op3<MX>(B.x,B.y,B.z));
}
template<bool MX> __device__ __forceinline__ float4 shift3c(float4 A, float4 B) {
    return mk4(op3<MX>(A.z,A.w,B.x), op3<MX>(A.w,B.x,B.y),
               op3<MX>(B.x,B.y,B.z), op3<MX>(B.y,B.z,B.w));
}
template<bool MX> __device__ __forceinline__ float4 xy3(const float* base, int stride, int y, int xq) {
    float4 acc;
    #pragma unroll
    for (int dy = 0; dy < 3; ++dy) {
        const float* row = base + (y + dy) * stride + xq * 4;
        float4 m = shift3<MX>(ldf4(row), ldf4(row + 4));
        acc = dy ? vop<MX>(acc, m) : m;
    }
    return acc;
}
__device__ __forceinline__ float4 maskq(float4 v, int gx0, int gy, int gz, float NEUT) {
    const bool okzy = ((unsigned)gz < DIMD) & ((unsigned)gy < DIMH);
    float4 r;
    r.x = (okzy & ((unsigned)(gx0 + 0) < DIMW)) ? v.x : NEUT;
    r.y = (okzy & ((unsigned)(gx0 + 1) < DIMW)) ? v.y : NEUT;
    r.z = (okzy & ((unsigned)(gx0 + 2) < DIMW)) ? v.z : NEUT;
    r.w = (okzy & ((unsigned)(gx0 + 3) < DIMW)) ? v.w : NEUT;
    return r;
}
__device__ __forceinline__ float4 relu_sub(float4 a, float4 b) {
    return mk4(fmaxf(a.x-b.x,0.f), fmaxf(a.y-b.y,0.f), fmaxf(a.z-b.z,0.f), fmaxf(a.w-b.w,0.f));
}
__device__ __forceinline__ float4 skup(float4 sk, float4 dl) {
    sk.x += fmaxf(dl.x - sk.x*dl.x, 0.f);
    sk.y += fmaxf(dl.y - sk.y*dl.y, 0.f);
    sk.z += fmaxf(dl.z - sk.z*dl.z, 0.f);
    sk.w += fmaxf(dl.w - sk.w*dl.w, 0.f);
    return sk;
}

// -------- prologue --------
__global__ __launch_bounds__(256) void prologue_kernel(const float* __restrict__ yp,
                                                       const float* __restrict__ yt,
                                                       float* __restrict__ img) {
    int i = blockIdx.x * 256 + threadIdx.x;
    if (i < N4) {
        float4 a = ldf4(yp + i * 4);
        float4 b = ldf4(yt + i * 4);
        float4 s = mk4(sigmoidf_(sigmoidf_(a.x)), sigmoidf_(sigmoidf_(a.y)),
                       sigmoidf_(sigmoidf_(a.z)), sigmoidf_(sigmoidf_(a.w)));
        *(float4*)(img + i * 4) = s;
        *(float4*)(img + N_ELEM + i * 4) = b;
    }
}

// ======== fused 2-iteration kernel ========
// V = I_{2j}. e1 = erode(V) = I_{2j+1}; e2 = erode(e1) = I_{2j+2} (-> eout).
// delta_{2j}   = relu(V  - dilate(e1));  delta_{2j+1} = relu(e1 - dilate(e2)).
// MODE 0: skel = delta_{2j} then update with delta_{2j+1} (no skel read).
// MODE 1: skel = RMW with both deltas sequentially.
// Tile 32x8 outputs, z-chunk 12, 21 steps, skewed single-barrier pipeline.
// Wave roles: w0=E1(60 tasks,8-wide), w1=E2(50,8-wide), w2=D1(64,4-wide), w3=D2(64,4-wide).
// Skew (write at step s, visible after barrier of s):
//   IP[s%5]  <- plane bz-3+s,           s in [0,17]
//   E1A[s%2] (+inf mask), E1B[s%5] (-inf mask) <- e1 plane bz-5+s, s in [3,18]
//   E2A[s%3] (-inf mask) <- e2 plane bz-7+s,   s in [6,19]
//   SK[s%3]  <- skel-after-delta_{2j} for plane bz+s-7 (D1), s in [7,18]
//   D2 final output plane bz+s-9,              s in [9,20]
// Reads at step s: E1<-IP[(s-1)%5]; E2<-E1A[(s-1)%2]; D1 stencil<-E1B[(s-1)%5],
//   aux V<-IP[(s-4)%5]; D2 stencil<-E2A[(s-1)%3], aux e1<-E1B[(s-4)%5],
//   eout e2<-E2A[(s-2)%3], sk<-SK[(s-2)%3].  All writer/reader slots distinct.
template<int MODE>
__global__ __launch_bounds__(256) void fused_kernel(const float* __restrict__ V,
                                                    float* __restrict__ eout,
                                                    float* __restrict__ skel) {
    __shared__ alignas(16) float IP[5][14 * 44];   // origin (bx-4, by-3), 40 wide used
    __shared__ alignas(16) float E1A[2][12 * 44];  // origin (bx-3, by-2), +inf masked
    __shared__ alignas(16) float E1B[5][12 * 44];  // origin (bx-3, by-2), -inf masked
    __shared__ alignas(16) float E2A[3][10 * 40];  // origin (bx-2, by-1), -inf masked
    __shared__ alignas(16) float SK[3][8 * 32];    // skel after first delta
    const int tid = threadIdx.x;
    const int vol = blockIdx.z >> 3, zc = blockIdx.z & 7;
    const int bx = blockIdx.x * 32, by = blockIdx.y * 8, bz = zc * 12;
    const float* s = V + (size_t)vol * N_ELEM;

    const int w = tid >> 6, lt = tid & 63;
    const int eo = lt % 5, er = lt / 5;       // E1/E2 task coords (8-wide octet, row)
    const int dq = lt & 7,  dr = lt >> 3;     // D1/D2 task coords (4-wide quad, row)
    const bool isE1 = (w == 0) && (lt < 60);
    const bool isE2 = (w == 1) && (lt < 50);
    const bool isD1 = (w == 2);
    const bool isD2 = (w == 3);

    // loads: IP plane = 14 rows x 40 cols = 560 elems
    int goff[3], loff[3]; bool fok[3];
    #pragma unroll
    for (int k = 0; k < 3; ++k) {
        int f = tid + k * 256;
        fok[k] = f < 560;
        int ly = f / 40, lx = f - ly * 40;
        int gy = min(max(by - 3 + ly, 0), DIMH - 1);
        int gx = min(max(bx - 4 + lx, 0), DIMW - 1);
        goff[k] = fok[k] ? gy * DIMW + gx : 0;
        loff[k] = ly * 44 + lx;
    }

    // shared ring registers (each thread belongs to exactly one stage)
    float4 rA0{}, rA1{}, rB0{}, rB1{}, rC0{}, rC1{};
    float lvA[3], lvB[3];
    float4 skA{}, skB{};

    auto issue = [&](int p, float (&lv)[3]) {
        const int zcl = min(max(bz - 3 + p, 0), DIMD - 1);
        const float* sp = s + (size_t)zcl * DIMH * DIMW;
        #pragma unroll
        for (int k = 0; k < 3; ++k) if (fok[k]) lv[k] = sp[goff[k]];
    };
    auto commit = [&](const float (&lv)[3], float* dp) {
        #pragma unroll
        for (int k = 0; k < 3; ++k) if (fok[k]) dp[loff[k]] = lv[k];
    };
    auto d_gi = [&](int zplane) -> size_t {
        return (size_t)vol * N_ELEM + ((size_t)zplane * DIMH + (by + dr)) * DIMW + bx + dq * 4;
    };
    auto issue_sk = [&](int u, float4& r) {
        if (MODE == 1 && isD1 && u >= 7 && u <= 18) r = ldf4(skel + d_gi(bz + u - 7));
    };

    auto stages = [&](int st, const float4& sk4) {
        if (isE1 && st >= 1 && st <= 18) {
            // xy-min (8-wide) of IP plane bz-4+st
            const float* ip = IP[(st - 1) % 5];
            float4 x0, x1;
            #pragma unroll
            for (int dy = 0; dy < 3; ++dy) {
                const float* row = ip + (er + dy) * 44 + eo * 8;
                float4 A = ldf4(row), B = ldf4(row + 4), C = ldf4(row + 8);
                float4 q0 = shift3<false>(A, B), q1 = shift3<false>(B, C);
                if (dy) { x0 = vop<false>(x0, q0); x1 = vop<false>(x1, q1); }
                else    { x0 = q0; x1 = q1; }
            }
            rA0 = rB0; rA1 = rB1; rB0 = rC0; rB1 = rC1; rC0 = x0; rC1 = x1;
            if (st >= 3) {
                float4 z0 = vop<false>(vop<false>(rA0, rB0), rC0);
                float4 z1 = vop<false>(vop<false>(rA1, rB1), rC1);
                const int gx0 = bx - 3 + eo * 8, gy = by - 2 + er, gz = bz - 5 + st;
                float* a = &E1A[st & 1][er * 44 + eo * 8];
                float* b = &E1B[st % 5][er * 44 + eo * 8];
                *(float4*)(a)     = maskq(z0, gx0,     gy, gz,  INFINITY);
                *(float4*)(a + 4) = maskq(z1, gx0 + 4, gy, gz,  INFINITY);
                *(float4*)(b)     = maskq(z0, gx0,     gy, gz, -INFINITY);
                *(float4*)(b + 4) = maskq(z1, gx0 + 4, gy, gz, -INFINITY);
            }
        }
        if (isE2 && st >= 4 && st <= 19) {
            // xy-min (8-wide) of e1 plane bz-6+st (from +inf-masked copy)
            const float* e1 = E1A[(st - 1) & 1];
            float4 x0, x1;
            #pragma unroll
            for (int dy = 0; dy < 3; ++dy) {
                const float* row = e1 + (er + dy) * 44 + eo * 8;
                float4 A = ldf4(row), B = ldf4(row + 4), C = ldf4(row + 8);
                float4 q0 = shift3<false>(A, B), q1 = shift3<false>(B, C);
                if (dy) { x0 = vop<false>(x0, q0); x1 = vop<false>(x1, q1); }
                else    { x0 = q0; x1 = q1; }
            }
            rA0 = rB0; rA1 = rB1; rB0 = rC0; rB1 = rC1; rC0 = x0; rC1 = x1;
            if (st >= 6) {
                float4 z0 = vop<false>(vop<false>(rA0, rB0), rC0);
                float4 z1 = vop<false>(vop<false>(rA1, rB1), rC1);
                const int gx0 = bx - 2 + eo * 8, gy = by - 1 + er, gz = bz - 7 + st;
                float* d = &E2A[st % 3][er * 40 + eo * 8];
                *(float4*)(d)     = maskq(z0, gx0,     gy, gz, -INFINITY);
                *(float4*)(d + 4) = maskq(z1, gx0 + 4, gy, gz, -INFINITY);
            }
        }
        if (isD1 && st >= 4 && st <= 18) {
            // xy-max (4-wide) of e1 plane bz-6+st; window offset +2 in quad frame
            const float* e1 = E1B[(st - 1) % 5];
            float4 x0;
            #pragma unroll
            for (int dy = 0; dy < 3; ++dy) {
                const float* row = e1 + (dr + 1 + dy) * 44 + dq * 4;
                float4 A = ldf4(row), B = ldf4(row + 4);
                float4 m = shift3c<true>(A, B);
                x0 = dy ? vop<true>(x0, m) : m;
            }
            rA0 = rB0; rB0 = rC0; rC0 = x0;
            if (st >= 7) {
                float4 D = vop<true>(vop<true>(rA0, rB0), rC0);
                // aux = V (=I_{2j}) at output: IP plane bz+st-7, row dr+3, x idx dq*4+4
                const float* ar = &IP[(st - 4) % 5][(dr + 3) * 44 + dq * 4 + 4];
                float4 av = ldf4(ar);
                float4 dl = relu_sub(av, D);
                float4 sk1 = (MODE == 0) ? dl : skup(sk4, dl);
                *(float4*)&SK[st % 3][dr * 32 + dq * 4] = sk1;
            }
        }
        if (isD2 && st >= 7 && st <= 20) {
            // xy-max (4-wide) of e2 plane bz-8+st; window offset +1 in quad frame
            const float* e2 = E2A[(st - 1) % 3];
            float4 x0;
            #pragma unroll
            for (int dy = 0; dy < 3; ++dy) {
                const float* row = e2 + (dr + dy) * 40 + dq * 4;
                float4 A = ldf4(row), B = ldf4(row + 4);
                float4 m = shift3b<true>(A, B);
                x0 = dy ? vop<true>(x0, m) : m;
            }
            rA0 = rB0; rB0 = rC0; rC0 = x0;
            if (st >= 9) {
                float4 D = vop<true>(vop<true>(rA0, rB0), rC0);
                const int zd = bz + st - 9;
                // aux = e1 (=I_{2j+1}) at output: E1B plane zd (written st-4), row dr+2, idx dq*4+3
                const float* ax = &E1B[(st - 4) % 5][(dr + 2) * 44 + dq * 4];
                float4 Aa = ldf4(ax), Ba = ldf4(ax + 4);
                float4 av = mk4(Aa.w, Ba.x, Ba.y, Ba.z);
                // eout = e2 (=I_{2j+2}) at output: E2A plane zd (written st-2), row dr+1, idx dq*4+2
                const float* ex = &E2A[(st - 2) % 3][(dr + 1) * 40 + dq * 4];
                float4 Ae = ldf4(ex), Be = ldf4(ex + 4);
                float4 ev = mk4(Ae.z, Ae.w, Be.x, Be.y);
                float4 sk1 = ldf4(&SK[(st - 2) % 3][dr * 32 + dq * 4]);
                float4 dl = relu_sub(av, D);
                float4 skf = skup(sk1, dl);
                const size_t gi = d_gi(zd);
                *(float4*)(skel + gi) = skf;
                *(float4*)(eout + gi) = ev;
            }
        }
    };

    issue(0, lvA);
    issue(1, lvB);
    issue_sk(7, skB);   // first odd consume; first even consume (u=8) issued in-loop at s=6
    for (int st = 0; st < 21; st += 2) {
        if (st < 18) commit(lvA, IP[st % 5]);
        if (st + 2 < 18) issue(st + 2, lvA);
        stages(st, skA);
        issue_sk(st + 2, skA);
        pipe_barrier();
        const int s1 = st + 1;
        if (s1 < 21) {
            if (s1 < 18) commit(lvB, IP[s1 % 5]);
            if (s1 + 2 < 18) issue(s1 + 2, lvB);
            stages(s1, skB);
            issue_sk(s1 + 2, skB);
            pipe_barrier();
        }
    }
}

// -------- single-iteration tail kernel (delta_16), verified structure from Round 8 --------
template<int EPI>
__global__ __launch_bounds__(256) void morph_kernel(const float* __restrict__ V,
                                                    float* __restrict__ eout,
                                                    float* __restrict__ skel) {
    __shared__ alignas(16) float IP[5][12 * 40];
    __shared__ alignas(16) float E[4][10 * 36];
    const int tid = threadIdx.x;
    const int vol = blockIdx.z >> 3, zc = blockIdx.z & 7;
    const int bx = blockIdx.x * 32, by = blockIdx.y * 8, bz = zc * 12;
    const float* s = V + (size_t)vol * N_ELEM;

    const int eid = (tid < 90) ? tid : -1;
    const int did = (tid >= 128 && tid < 192) ? tid - 128 : -1;
    const int eq = (eid >= 0) ? eid % 9 : 0, ey = (eid >= 0) ? eid / 9 : 0;
    const int dq = (did >= 0) ? (did & 7) : 0, dyy = (did >= 0) ? (did >> 3) : 0;

    int goff[2], loff[2]; bool fok[2];
    #pragma unroll
    for (int k = 0; k < 2; ++k) {
        int f = tid + k * 256;
        fok[k] = f < 456;
        int ly = f / 38, lx = f - ly * 38;
        int gy = min(max(by - 2 + ly, 0), DIMH - 1);
        int gx = min(max(bx - 2 + lx, 0), DIMW - 1);
        goff[k] = fok[k] ? gy * DIMW + gx : 0;
        loff[k] = ly * 40 + lx;
    }

    float4 r1a{}, r1b{}, r1c{}, r2a{}, r2b{}, r2c{};
    float lvA[2], lvB[2];
    float4 skA{}, skB{};

    auto issue = [&](int p, float (&lv)[2]) {
        const int zcl = min(max(bz - 2 + p, 0), DIMD - 1);
        const float* sp = s + (size_t)zcl * DIMH * DIMW;
        #pragma unroll
        for (int k = 0; k < 2; ++k) lv[k] = sp[goff[k]];
    };
    auto commit = [&](const float (&lv)[2], float* dp) {
        #pragma unroll
        for (int k = 0; k < 2; ++k) if (fok[k]) dp[loff[k]] = lv[k];
    };
    auto sk_gi = [&](int st) -> size_t {
        const int zd = bz - 6 + st;
        return (size_t)vol * N_ELEM + ((size_t)zd * DIMH + (by + dyy)) * DIMW + bx + dq * 4;
    };
    auto issue_sk = [&](int st, float4& r) {
        if (EPI == 2 && did >= 0 && st >= 6 && st <= 17) r = ldf4(skel + sk_gi(st));
    };
    auto stages = [&](int st, const float4& sk4) {
        if (eid >= 0 && st >= 1 && st <= 16) {
            float4 a1 = xy3<false>(IP[(st - 1) % 5], 40, ey, eq);
            r1a = r1b; r1b = r1c; r1c = a1;
            if (st >= 3) {
                float4 e1 = vop<false>(vop<false>(r1a, r1b), r1c);
                e1 = maskq(e1, bx - 1 + eq * 4, by - 1 + ey, bz - 4 + st, -INFINITY);
                *(float4*)&E[st & 3][ey * 36 + eq * 4] = e1;
            }
        }
        if (did >= 0 && st >= 4 && st <= 17) {
            float4 a2 = xy3<true>(E[(st - 1) & 3], 36, dyy, dq);
            r2a = r2b; r2b = r2c; r2c = a2;
            if (st >= 6) {
                float4 D = vop<true>(vop<true>(r2a, r2b), r2c);
                const float* ar = &IP[(st - 4) % 5][(dyy + 2) * 40 + dq * 4];
                float4 P = ldf4(ar), Q = ldf4(ar + 4);
                float4 av = mk4(P.z, P.w, Q.x, Q.y);
                const float* er = &E[(st - 2) & 3][(dyy + 1) * 36 + dq * 4];
                float4 R = ldf4(er), S = ldf4(er + 4);
                float4 ev = mk4(R.y, R.z, R.w, S.x);
                const size_t gi = sk_gi(st);
                float4 dl = relu_sub(av, D);
                if (EPI == 1) {
                    *(float4*)(skel + gi) = dl;
                } else {
                    *(float4*)(skel + gi) = skup(sk4, dl);
                }
                *(float4*)(eout + gi) = ev;
            }
        }
    };

    issue(0, lvA);
    issue(1, lvB);
    issue_sk(6, skA);
    issue_sk(7, skB);
    for (int st = 0; st < 18; st += 2) {
        if (st < 16) commit(lvA, IP[st % 5]);
        if (st + 2 < 16) issue(st + 2, lvA);
        stages(st, skA);
        issue_sk(st + 2, skA);
        pipe_barrier();
        const int s1 = st + 1;
        if (s1 < 16) commit(lvB, IP[s1 % 5]);
        if (s1 + 2 < 16) issue(s1 + 2, lvB);
        stages(s1, skB);
        issue_sk(s1 + 2, skB);
        pipe_barrier();
    }
}

// -------- reductions --------
__device__ __forceinline__ double wave_block_reduce(double v, double* red4) {
    for (int off = 32; off > 0; off >>= 1) v += __shfl_down(v, off, 64);
    int wid = threadIdx.x >> 6, lane = threadIdx.x & 63;
    if (lane == 0) red4[wid] = v;
    __syncthreads();
    double r = red4[0] + red4[1] + red4[2] + red4[3];
    __syncthreads();
    return r;
}

__global__ __launch_bounds__(256) void reduce_partial(const float* __restrict__ yp,
                                                      const float* __restrict__ yt,
                                                      const float* __restrict__ sp,
                                                      const float* __restrict__ st,
                                                      double* __restrict__ partials) {
    double acc[10];
    #pragma unroll
    for (int k = 0; k < 10; ++k) acc[k] = 0.0;

    for (int i = blockIdx.x * 256 + threadIdx.x; i < N4; i += RBLOCKS * 256) {
        float4 x = ldf4(yp + i * 4);
        float4 t = ldf4(yt + i * 4);
        float4 a = ldf4(sp + i * 4);
        float4 b = ldf4(st + i * 4);
        #pragma unroll
        for (int c = 0; c < 4; ++c) {
            float xc = (&x.x)[c], tc = (&t.x)[c], ac = (&a.x)[c], bc = (&b.x)[c];
            float s1 = sigmoidf_(xc);
            float s2 = sigmoidf_(s1);
            float w  = expf(-0.5f * bc * bc);
            acc[0] += (double)(ac * tc);
            acc[1] += (double)ac;
            acc[2] += (double)(bc * s2);
            acc[3] += (double)bc;
            acc[4] += (double)(w * s1 * tc);
            acc[5] += (double)(w * s1);
            acc[6] += (double)(w * tc);
            acc[7] += (double)(s1 * tc);
            acc[8] += (double)s1;
            acc[9] += (double)tc;
        }
    }

    __shared__ double red4[4];
    #pragma unroll
    for (int k = 0; k < 10; ++k) {
        double r = wave_block_reduce(acc[k], red4);
        if (threadIdx.x == 0) partials[blockIdx.x * 10 + k] = r;
        __syncthreads();
    }
}

__global__ __launch_bounds__(256) void finalize_kernel(const double* __restrict__ partials,
                                                       float* __restrict__ out) {
    __shared__ double sums[10];
    __shared__ double red4[4];
    for (int k = 0; k < 10; ++k) {
        double v = 0.0;
        for (int j = threadIdx.x; j < RBLOCKS; j += 256) v += partials[j * 10 + k];
        double r = wave_block_reduce(v, red4);
        if (threadIdx.x == 0) sums[k] = r;
        __syncthreads();
    }
    if (threadIdx.x == 0) {
        double tprec = (sums[0] + 1.0) / (sums[1] + 1.0);
        double tsens = (sums[2] + 1.0) / (sums[3] + 1.0);
        double cldice = 1.0 - 2.0 * (tprec * tsens) / (tprec + tsens + 1.0);
        double boundary = 1.0 - (2.0 * sums[4] + 1.0) / (sums[5] + sums[6] + 1.0);
        double dice = 1.0 - (2.0 * sums[7] + 1.0) / (sums[8] + sums[9] + 1.0);
        out[0] = (float)(0.5 * cldice + 0.3 * boundary + 0.2 * dice);
    }
}

extern "C" void kernel_launch(void* const* d_in, const int* in_sizes, int n_in,
                              void* d_out, int out_size, void* d_ws, size_t ws_size,
                              hipStream_t stream) {
    const float* y_pred = (const float*)d_in[0];
    const float* y_true = (const float*)d_in[1];
    float* out = (float*)d_out;

    const size_t NB = (size_t)2 * N_ELEM;
    float* imgA = (float*)d_ws;      // I_{2j} ping-pong
    float* imgB = imgA + NB;
    float* skel = imgB + NB;
    double* partials = (double*)(skel + NB);

    dim3 g(DIMW / 32, DIMH / 8, 8 * 2);   // (4, 16, 16); z = vol*8 + zchunk(12 deep)
    dim3 b(256);

    prologue_kernel<<<(N4 + 255) / 256, 256, 0, stream>>>(y_pred, y_true, imgA);

    // delta_0, delta_1; eout = I_2
    fused_kernel<0><<<g, b, 0, stream>>>(imgA, imgB, skel);
    float* cur = imgB;   // I_{2j}
    float* nxt = imgA;
    for (int j = 1; j < 8; ++j) {
        // delta_{2j}, delta_{2j+1}; eout = I_{2j+2}
        fused_kernel<1><<<g, b, 0, stream>>>(cur, nxt, skel);
        float* tmp = cur; cur = nxt; nxt = tmp;
    }
    // cur = I_16: final delta_16
    morph_kernel<2><<<g, b, 0, stream>>>(cur, nxt, skel);

    reduce_partial<<<RBLOCKS, 256, 0, stream>>>(y_pred, y_true, skel, skel + N_ELEM, partials);
    finalize_kernel<<<1, 256, 0, stream>>>(partials, out);
}